// Round 1
// baseline (246.112 us; speedup 1.0000x reference)
//
#include <hip/hip_runtime.h>
#include <cstdint>
#include <cstddef>

typedef __attribute__((ext_vector_type(8))) short bf16x8;
typedef __attribute__((ext_vector_type(4))) float f32x4;
typedef unsigned short u16;

__device__ inline u16 f2bf(float x) {
  uint32_t u = __builtin_bit_cast(uint32_t, x);
  u += 0x7FFFu + ((u >> 16) & 1u);
  return (u16)(u >> 16);
}

__device__ inline void gload_lds16(const void* g, void* l) {
  __builtin_amdgcn_global_load_lds(
      (const __attribute__((address_space(1))) char*)g,
      (__attribute__((address_space(3))) char*)l, 16, 0, 0);
}

// ---------------- weight f32 -> bf16 convert ----------------
__global__ __launch_bounds__(256) void cvt_bf16(const float* __restrict__ in,
                                                u16* __restrict__ out, int n) {
  int i = (blockIdx.x * blockDim.x + threadIdx.x) * 4;
  if (i >= n) return;
  float4 v = *reinterpret_cast<const float4*>(in + i);
  u16 o[4] = {f2bf(v.x), f2bf(v.y), f2bf(v.z), f2bf(v.w)};
  *reinterpret_cast<uint2*>(out + i) = *reinterpret_cast<const uint2*>(o);
}

// ---------------- GroupNorm stats: per-channel scale/shift ----------------
// 32 groups x (16 ch * 4096 px). sc[c] = w[c]*rstd(g); sh[c] = b[c]-mu*rstd*w[c]
__global__ __launch_bounds__(256) void gn_stats(const float* __restrict__ x,
                                                const float* __restrict__ w,
                                                const float* __restrict__ b,
                                                float* __restrict__ sc,
                                                float* __restrict__ sh) {
  __shared__ float rs[4], rss[4];
  int g = blockIdx.x;
  const float* base = x + (size_t)g * 16 * 4096;
  int t = threadIdx.x;
  float s = 0.f, ss = 0.f;
  for (int i = t * 4; i < 65536; i += 1024) {
    float4 v = *reinterpret_cast<const float4*>(base + i);
    s += v.x + v.y + v.z + v.w;
    ss += v.x * v.x + v.y * v.y + v.z * v.z + v.w * v.w;
  }
  for (int d = 32; d; d >>= 1) {
    s += __shfl_down(s, d, 64);
    ss += __shfl_down(ss, d, 64);
  }
  int wid = t >> 6;
  if ((t & 63) == 0) { rs[wid] = s; rss[wid] = ss; }
  __syncthreads();
  if (t < 16) {
    float S = rs[0] + rs[1] + rs[2] + rs[3];
    float SS = rss[0] + rss[1] + rss[2] + rss[3];
    float mu = S / 65536.f;
    float var = SS / 65536.f - mu * mu;
    float rstd = rsqrtf(var + 1e-5f);
    int c = g * 16 + t;
    sc[c] = w[c] * rstd;
    sh[c] = b[c] - mu * rstd * w[c];
  }
}

// ---------------- normalize (optional) + transpose to token-major bf16 ------
// in: f32 [C][4096]  ->  out: bf16 [4096][C].  sc/sh null => plain transpose.
__global__ __launch_bounds__(256) void transpose_norm(const float* __restrict__ in,
                                                      u16* __restrict__ out, int C,
                                                      const float* __restrict__ sc,
                                                      const float* __restrict__ sh) {
  __shared__ float tile[64][65];
  int p0 = blockIdx.x * 64, c0 = blockIdx.y * 64;
  int t = threadIdx.x;
  int cl = t >> 4, pl = (t & 15) * 4;
#pragma unroll
  for (int rep = 0; rep < 4; ++rep) {
    int c = cl + rep * 16;
    float4 v = *reinterpret_cast<const float4*>(in + (size_t)(c0 + c) * 4096 + p0 + pl);
    float s = 1.f, f = 0.f;
    if (sc) { s = sc[c0 + c]; f = sh[c0 + c]; }
    tile[c][pl + 0] = v.x * s + f;
    tile[c][pl + 1] = v.y * s + f;
    tile[c][pl + 2] = v.z * s + f;
    tile[c][pl + 3] = v.w * s + f;
  }
  __syncthreads();
#pragma unroll
  for (int rep = 0; rep < 16; ++rep) {
    int idx = rep * 256 + t;
    int pw = idx >> 6, cw = idx & 63;
    out[(size_t)(p0 + pw) * C + c0 + cw] = f2bf(tile[cw][pw]);
  }
}

// ---------------- NT GEMM: D[i][j] = sum_k A[i][k]*B[j][k] -------------------
// A: bf16 [Ra][K], B: bf16 [Rb][K], row-major, K%64==0, Ra,Rb %128==0.
// BIAS_MODE: 0 = bias[i], 1 = bias[j]. OUT_BF16: store bf16 else f32.
// ADD_RES: D += res[i*Rb+j] (f32). oscale applied after bias.
template <int BIAS_MODE, bool OUT_BF16, bool ADD_RES>
__global__ __launch_bounds__(256) void gemm_nt(const u16* __restrict__ A,
                                               const u16* __restrict__ B,
                                               void* __restrict__ Dv,
                                               const float* __restrict__ bias,
                                               const float* __restrict__ res,
                                               int Ra, int Rb, int K, float oscale) {
  __shared__ u16 aT[128 * 64];
  __shared__ u16 bT[128 * 64];
  const int t = threadIdx.x;
  const int lane = t & 63, w = t >> 6;
  const int wr = w >> 1, wc = w & 1;
  const int l15 = lane & 15, l4 = lane >> 4;
  const int i0 = blockIdx.y * 128, j0 = blockIdx.x * 128;
  const int r_st = t >> 3, slot = t & 7;
  f32x4 acc[4][4] = {};

  for (int kt = 0; kt < K; kt += 64) {
    // stage A,B tiles (128x64 bf16 each), pre-swizzled global source (G21)
#pragma unroll
    for (int q = 0; q < 4; ++q) {
      int row = q * 32 + r_st;
      int koff = kt + ((slot ^ (row & 7)) * 8);
      gload_lds16(A + (size_t)(i0 + row) * K + koff, (char*)aT + q * 4096 + w * 1024);
      gload_lds16(B + (size_t)(j0 + row) * K + koff, (char*)bT + q * 4096 + w * 1024);
    }
    __syncthreads();
#pragma unroll
    for (int kk = 0; kk < 2; ++kk) {
      bf16x8 af[4], bf[4];
#pragma unroll
      for (int m = 0; m < 4; ++m) {
        int row = wr * 64 + m * 16 + l15;
        int off = row * 128 + ((l4 * 16 + kk * 64) ^ ((row & 7) << 4));
        af[m] = *reinterpret_cast<const bf16x8*>((const char*)aT + off);
      }
#pragma unroll
      for (int n = 0; n < 4; ++n) {
        int row = wc * 64 + n * 16 + l15;
        int off = row * 128 + ((l4 * 16 + kk * 64) ^ ((row & 7) << 4));
        bf[n] = *reinterpret_cast<const bf16x8*>((const char*)bT + off);
      }
#pragma unroll
      for (int m = 0; m < 4; ++m)
#pragma unroll
        for (int n = 0; n < 4; ++n)
          acc[m][n] = __builtin_amdgcn_mfma_f32_16x16x32_bf16(af[m], bf[n], acc[m][n], 0, 0, 0);
    }
    __syncthreads();
  }

#pragma unroll
  for (int m = 0; m < 4; ++m) {
    int ib = i0 + wr * 64 + m * 16 + l4 * 4;
#pragma unroll
    for (int n = 0; n < 4; ++n) {
      int j = j0 + wc * 64 + n * 16 + l15;
#pragma unroll
      for (int r = 0; r < 4; ++r) {
        int i = ib + r;
        float v = acc[m][n][r];
        if (BIAS_MODE == 0) v += bias[i];
        else v += bias[j];
        v *= oscale;
        if (ADD_RES) v += res[(size_t)i * Rb + j];
        if (OUT_BF16)
          ((u16*)Dv)[(size_t)i * Rb + j] = f2bf(v);
        else
          ((float*)Dv)[(size_t)i * Rb + j] = v;
      }
    }
  }
}

// ---------------- flash attention --------------------------------------------
// QT,KT: bf16 [4096][512] token-major (Q pre-scaled by 1/8). V: bf16 [512][4096]
// d-major. Ot: bf16 [4096][512] token-major output.
// grid: (64 q-tiles, 8 heads), 256 threads = 4 waves x 16 q-rows.
__global__ __launch_bounds__(256) void attn_kernel(const u16* __restrict__ QT,
                                                   const u16* __restrict__ KT,
                                                   const u16* __restrict__ V,
                                                   u16* __restrict__ Ot) {
  __shared__ u16 kbuf[64 * 64];
  __shared__ u16 vbuf[64 * 64];
  __shared__ u16 pbuf[4][16 * 64];
  const int t = threadIdx.x;
  const int lane = t & 63, w = t >> 6;
  const int l15 = lane & 15, l4 = lane >> 4;
  const int h = blockIdx.y;
  const int q0 = blockIdx.x * 64;
  const int r_st = t >> 3, slot = t & 7;

  const int qrow = q0 + w * 16 + l15;
  bf16x8 qa0 = *reinterpret_cast<const bf16x8*>(QT + (size_t)qrow * 512 + h * 64 + l4 * 8);
  bf16x8 qa1 = *reinterpret_cast<const bf16x8*>(QT + (size_t)qrow * 512 + h * 64 + 32 + l4 * 8);

  f32x4 o_acc[4] = {};
  float m_run[4], l_run[4];
#pragma unroll
  for (int r = 0; r < 4; ++r) { m_run[r] = -1e30f; l_run[r] = 0.f; }

  u16* pw = pbuf[w];

  for (int kt = 0; kt < 64; ++kt) {
    int jb = kt * 64;
    // stage K tile [64 tok][64 d] and V tile [64 d][64 tok], swizzled
#pragma unroll
    for (int q = 0; q < 2; ++q) {
      int row = q * 32 + r_st;
      int so = (slot ^ (row & 7)) * 8;
      gload_lds16(KT + (size_t)(jb + row) * 512 + h * 64 + so,
                  (char*)kbuf + q * 4096 + w * 1024);
      gload_lds16(V + (size_t)(h * 64 + row) * 4096 + jb + so,
                  (char*)vbuf + q * 4096 + w * 1024);
    }
    __syncthreads();

    // S = Q K^T  (wave's 16 rows x 64 keys)
    f32x4 s[4];
#pragma unroll
    for (int n = 0; n < 4; ++n) {
      int row = n * 16 + l15;
      int b0 = row * 128 + ((l4 * 16) ^ ((row & 7) << 4));
      int b1 = row * 128 + ((l4 * 16 + 64) ^ ((row & 7) << 4));
      bf16x8 kb0 = *reinterpret_cast<const bf16x8*>((const char*)kbuf + b0);
      bf16x8 kb1 = *reinterpret_cast<const bf16x8*>((const char*)kbuf + b1);
      f32x4 z = {};
      z = __builtin_amdgcn_mfma_f32_16x16x32_bf16(qa0, kb0, z, 0, 0, 0);
      z = __builtin_amdgcn_mfma_f32_16x16x32_bf16(qa1, kb1, z, 0, 0, 0);
      s[n] = z;
    }

    // online softmax; row i_loc = l4*4+r lives in 16 lanes (l15) x 4 frags
    float alpha[4];
#pragma unroll
    for (int r = 0; r < 4; ++r) {
      float mx = fmaxf(fmaxf(s[0][r], s[1][r]), fmaxf(s[2][r], s[3][r]));
#pragma unroll
      for (int d = 1; d < 16; d <<= 1) mx = fmaxf(mx, __shfl_xor(mx, d, 64));
      float mn = fmaxf(m_run[r], mx);
      alpha[r] = __expf(m_run[r] - mn);
      m_run[r] = mn;
      float rs = 0.f;
#pragma unroll
      for (int n = 0; n < 4; ++n) {
        float p = __expf(s[n][r] - mn);
        s[n][r] = p;
        rs += p;
      }
#pragma unroll
      for (int d = 1; d < 16; d <<= 1) rs += __shfl_xor(rs, d, 64);
      l_run[r] = l_run[r] * alpha[r] + rs;
    }
#pragma unroll
    for (int dt = 0; dt < 4; ++dt)
#pragma unroll
      for (int r = 0; r < 4; ++r) o_acc[dt][r] *= alpha[r];

    // P -> per-wave LDS (transpose to A-fragment layout), swizzled
#pragma unroll
    for (int r = 0; r < 4; ++r) {
      int il = l4 * 4 + r;
#pragma unroll
      for (int n = 0; n < 4; ++n) {
        int j = n * 16 + l15;
        int off = (il * 128 + j * 2) ^ ((il & 7) << 4);
        *(u16*)((char*)pw + off) = f2bf(s[n][r]);
      }
    }
    __syncthreads();

    // O += P V
#pragma unroll
    for (int kk = 0; kk < 2; ++kk) {
      int poff = l15 * 128 + ((l4 * 16 + kk * 64) ^ ((l15 & 7) << 4));
      bf16x8 pa = *reinterpret_cast<const bf16x8*>((const char*)pw + poff);
#pragma unroll
      for (int dt = 0; dt < 4; ++dt) {
        int drow = dt * 16 + l15;
        int voff = drow * 128 + ((l4 * 16 + kk * 64) ^ ((drow & 7) << 4));
        bf16x8 vb = *reinterpret_cast<const bf16x8*>((const char*)vbuf + voff);
        o_acc[dt] = __builtin_amdgcn_mfma_f32_16x16x32_bf16(pa, vb, o_acc[dt], 0, 0, 0);
      }
    }
    __syncthreads();
  }

#pragma unroll
  for (int r = 0; r < 4; ++r) {
    float inv = 1.0f / l_run[r];
    int orow = q0 + w * 16 + l4 * 4 + r;
#pragma unroll
    for (int dt = 0; dt < 4; ++dt)
      Ot[(size_t)orow * 512 + h * 64 + dt * 16 + l15] = f2bf(o_acc[dt][r] * inv);
  }
}

// ---------------- host launch -------------------------------------------------
extern "C" void kernel_launch(void* const* d_in, const int* in_sizes, int n_in,
                              void* d_out, int out_size, void* d_ws, size_t ws_size,
                              hipStream_t stream) {
  const float* x    = (const float*)d_in[0];
  const float* ctx  = (const float*)d_in[1];
  const float* gn_w = (const float*)d_in[2];
  const float* gn_b = (const float*)d_in[3];
  const float* wq   = (const float*)d_in[4];
  const float* bq   = (const float*)d_in[5];
  const float* wk   = (const float*)d_in[6];
  const float* bk   = (const float*)d_in[7];
  const float* wv   = (const float*)d_in[8];
  const float* bv   = (const float*)d_in[9];
  const float* wo   = (const float*)d_in[10];
  const float* bo   = (const float*)d_in[11];

  char* ws = (char*)d_ws;
  float* sc   = (float*)ws;                       // 512 f32
  float* sh   = (float*)(ws + 2048);              // 512 f32
  u16* wqB    = (u16*)(ws + 4096);
  u16* wkB    = wqB + 512 * 512;
  u16* wvB    = wkB + 512 * 768;
  u16* woB    = wvB + 512 * 768;
  u16* hT     = woB + 512 * 512;                  // [4096][512]
  u16* ctxT   = hT + 4096 * 512;                  // [4096][768]
  u16* QT     = ctxT + 4096 * 768;                // [4096][512]
  u16* KT     = QT + 4096 * 512;                  // [4096][512]
  u16* Vb     = KT + 4096 * 512;                  // [512][4096]
  u16* OtT    = Vb + (size_t)512 * 4096;          // [4096][512]

  cvt_bf16<<<256, 256, 0, stream>>>(wq, wqB, 512 * 512);
  cvt_bf16<<<384, 256, 0, stream>>>(wk, wkB, 512 * 768);
  cvt_bf16<<<384, 256, 0, stream>>>(wv, wvB, 512 * 768);
  cvt_bf16<<<256, 256, 0, stream>>>(wo, woB, 512 * 512);

  gn_stats<<<32, 256, 0, stream>>>(x, gn_w, gn_b, sc, sh);
  transpose_norm<<<dim3(64, 8), 256, 0, stream>>>(x, hT, 512, sc, sh);
  transpose_norm<<<dim3(64, 12), 256, 0, stream>>>(ctx, ctxT, 768, nullptr, nullptr);

  // Q = hT x wq^T (scale 1/8 folded), K = ctxT x wk^T : [4096][512] token-major
  gemm_nt<1, true, false><<<dim3(4, 32), 256, 0, stream>>>(hT, wqB, QT, bq, nullptr, 4096, 512, 512, 0.125f);
  gemm_nt<1, true, false><<<dim3(4, 32), 256, 0, stream>>>(ctxT, wkB, KT, bk, nullptr, 4096, 512, 768, 1.0f);
  // V = wv x ctx : [512][4096] d-major
  gemm_nt<0, true, false><<<dim3(32, 4), 256, 0, stream>>>(wvB, ctxT, Vb, bv, nullptr, 512, 4096, 768, 1.0f);

  attn_kernel<<<dim3(64, 8), 256, 0, stream>>>(QT, KT, Vb, OtT);

  // out = wo x O + bo + residual(x), f32 [512][4096]
  gemm_nt<0, false, true><<<dim3(32, 4), 256, 0, stream>>>(woB, OtT, d_out, bo, x, 512, 4096, 512, 1.0f);
}

// Round 2
// 171.308 us; speedup vs baseline: 1.4367x; 1.4367x over previous
//
#include <hip/hip_runtime.h>
#include <cstdint>
#include <cstddef>

typedef __attribute__((ext_vector_type(8))) short bf16x8;
typedef __attribute__((ext_vector_type(4))) float f32x4;
typedef unsigned short u16;

__device__ inline u16 f2bf(float x) {
  uint32_t u = __builtin_bit_cast(uint32_t, x);
  u += 0x7FFFu + ((u >> 16) & 1u);
  return (u16)(u >> 16);
}

__device__ inline uint32_t cvtpk(float a, float b) {
  uint32_t r;
  asm("v_cvt_pk_bf16_f32 %0, %1, %2" : "=v"(r) : "v"(a), "v"(b));
  return r;
}

__device__ inline void gload_lds16(const void* g, void* l) {
  __builtin_amdgcn_global_load_lds(
      (const __attribute__((address_space(1))) char*)g,
      (__attribute__((address_space(3))) char*)l, 16, 0, 0);
}

// ---------------- weight f32 -> bf16 convert ----------------
__global__ __launch_bounds__(256) void cvt_bf16(const float* __restrict__ in,
                                                u16* __restrict__ out, int n) {
  int i = (blockIdx.x * blockDim.x + threadIdx.x) * 4;
  if (i >= n) return;
  float4 v = *reinterpret_cast<const float4*>(in + i);
  u16 o[4] = {f2bf(v.x), f2bf(v.y), f2bf(v.z), f2bf(v.w)};
  *reinterpret_cast<uint2*>(out + i) = *reinterpret_cast<const uint2*>(o);
}

// ---------------- GroupNorm stats: per-channel scale/shift ----------------
__global__ __launch_bounds__(256) void gn_stats(const float* __restrict__ x,
                                                const float* __restrict__ w,
                                                const float* __restrict__ b,
                                                float* __restrict__ sc,
                                                float* __restrict__ sh) {
  __shared__ float rs[4], rss[4];
  int g = blockIdx.x;
  const float* base = x + (size_t)g * 16 * 4096;
  int t = threadIdx.x;
  float s = 0.f, ss = 0.f;
  for (int i = t * 4; i < 65536; i += 1024) {
    float4 v = *reinterpret_cast<const float4*>(base + i);
    s += v.x + v.y + v.z + v.w;
    ss += v.x * v.x + v.y * v.y + v.z * v.z + v.w * v.w;
  }
  for (int d = 32; d; d >>= 1) {
    s += __shfl_down(s, d, 64);
    ss += __shfl_down(ss, d, 64);
  }
  int wid = t >> 6;
  if ((t & 63) == 0) { rs[wid] = s; rss[wid] = ss; }
  __syncthreads();
  if (t < 16) {
    float S = rs[0] + rs[1] + rs[2] + rs[3];
    float SS = rss[0] + rss[1] + rss[2] + rss[3];
    float mu = S / 65536.f;
    float var = SS / 65536.f - mu * mu;
    float rstd = rsqrtf(var + 1e-5f);
    int c = g * 16 + t;
    sc[c] = w[c] * rstd;
    sh[c] = b[c] - mu * rstd * w[c];
  }
}

// ---------------- normalize (optional) + transpose to token-major bf16 ------
__global__ __launch_bounds__(256) void transpose_norm(const float* __restrict__ in,
                                                      u16* __restrict__ out, int C,
                                                      const float* __restrict__ sc,
                                                      const float* __restrict__ sh) {
  __shared__ float tile[64][65];
  int p0 = blockIdx.x * 64, c0 = blockIdx.y * 64;
  int t = threadIdx.x;
  int cl = t >> 4, pl = (t & 15) * 4;
#pragma unroll
  for (int rep = 0; rep < 4; ++rep) {
    int c = cl + rep * 16;
    float4 v = *reinterpret_cast<const float4*>(in + (size_t)(c0 + c) * 4096 + p0 + pl);
    float s = 1.f, f = 0.f;
    if (sc) { s = sc[c0 + c]; f = sh[c0 + c]; }
    tile[c][pl + 0] = v.x * s + f;
    tile[c][pl + 1] = v.y * s + f;
    tile[c][pl + 2] = v.z * s + f;
    tile[c][pl + 3] = v.w * s + f;
  }
  __syncthreads();
#pragma unroll
  for (int rep = 0; rep < 16; ++rep) {
    int idx = rep * 256 + t;
    int pw = idx >> 6, cw = idx & 63;
    out[(size_t)(p0 + pw) * C + c0 + cw] = f2bf(tile[cw][pw]);
  }
}

// ---------------- NT GEMM: D[i][j] = sum_k A[i][k]*B[j][k] -------------------
// BM=128, BN template (64/128). Double-buffered LDS, one barrier per K-step.
template <int BN, int BIAS_MODE, bool OUT_BF16, bool ADD_RES>
__global__ __launch_bounds__(256) void gemm_nt(const u16* __restrict__ A,
                                               const u16* __restrict__ B,
                                               void* __restrict__ Dv,
                                               const float* __restrict__ bias,
                                               const float* __restrict__ res,
                                               int Ra, int Rb, int K, float oscale) {
  constexpr int NF = BN / 32;  // n-frags per wave (wave covers BN/2 cols)
  __shared__ u16 aT[2][128 * 64];
  __shared__ u16 bT[2][BN * 64];
  const int t = threadIdx.x;
  const int lane = t & 63, w = t >> 6;
  const int wr = w >> 1, wc = w & 1;
  const int l15 = lane & 15, l4 = lane >> 4;
  const int i0 = blockIdx.y * 128, j0 = blockIdx.x * BN;
  const int r_st = t >> 3, slot = t & 7;
  f32x4 acc[4][NF] = {};

  auto stage = [&](int kt, int b) {
#pragma unroll
    for (int q = 0; q < 4; ++q) {
      int row = q * 32 + r_st;
      int koff = kt + ((slot ^ (row & 7)) * 8);
      gload_lds16(A + (size_t)(i0 + row) * K + koff, (char*)aT[b] + q * 4096 + w * 1024);
    }
#pragma unroll
    for (int q = 0; q < BN / 32; ++q) {
      int row = q * 32 + r_st;
      int koff = kt + ((slot ^ (row & 7)) * 8);
      gload_lds16(B + (size_t)(j0 + row) * K + koff, (char*)bT[b] + q * 4096 + w * 1024);
    }
  };

  stage(0, 0);
  __syncthreads();

  int it = 0;
  for (int kt = 0; kt < K; kt += 64, ++it) {
    const int cur = it & 1;
    if (kt + 64 < K) stage(kt + 64, cur ^ 1);
#pragma unroll
    for (int kk = 0; kk < 2; ++kk) {
      bf16x8 af[4], bfr[NF];
#pragma unroll
      for (int m = 0; m < 4; ++m) {
        int row = wr * 64 + m * 16 + l15;
        int off = row * 128 + ((l4 * 16 + kk * 64) ^ ((row & 7) << 4));
        af[m] = *reinterpret_cast<const bf16x8*>((const char*)aT[cur] + off);
      }
#pragma unroll
      for (int n = 0; n < NF; ++n) {
        int row = wc * (BN / 2) + n * 16 + l15;
        int off = row * 128 + ((l4 * 16 + kk * 64) ^ ((row & 7) << 4));
        bfr[n] = *reinterpret_cast<const bf16x8*>((const char*)bT[cur] + off);
      }
#pragma unroll
      for (int m = 0; m < 4; ++m)
#pragma unroll
        for (int n = 0; n < NF; ++n)
          acc[m][n] = __builtin_amdgcn_mfma_f32_16x16x32_bf16(af[m], bfr[n], acc[m][n], 0, 0, 0);
    }
    __syncthreads();
  }

#pragma unroll
  for (int m = 0; m < 4; ++m) {
    int ib = i0 + wr * 64 + m * 16 + l4 * 4;
#pragma unroll
    for (int n = 0; n < NF; ++n) {
      int j = j0 + wc * (BN / 2) + n * 16 + l15;
#pragma unroll
      for (int r = 0; r < 4; ++r) {
        int i = ib + r;
        float v = acc[m][n][r];
        if (BIAS_MODE == 0) v += bias[i];
        else v += bias[j];
        v *= oscale;
        if (ADD_RES) v += res[(size_t)i * Rb + j];
        if (OUT_BF16)
          ((u16*)Dv)[(size_t)i * Rb + j] = f2bf(v);
        else
          ((float*)Dv)[(size_t)i * Rb + j] = v;
      }
    }
  }
}

// ---------------- flash attention (swapped QK^T, 1 barrier/iter) -------------
// QT,KT: bf16 [4096][512] token-major (Q pre-scaled by 1/8). V: bf16 [512][4096]
// d-major. Ot: bf16 [4096][512]. grid (64 q-tiles, 8 heads), 4 waves x 16 rows.
__global__ __launch_bounds__(256) void attn_kernel(const u16* __restrict__ QT,
                                                   const u16* __restrict__ KT,
                                                   const u16* __restrict__ V,
                                                   u16* __restrict__ Ot) {
  __shared__ u16 kbuf[2][64 * 64];
  __shared__ u16 vbuf[2][64 * 64];
  __shared__ u16 pbuf[4][16 * 64];
  const int t = threadIdx.x;
  const int lane = t & 63, w = t >> 6;
  const int l15 = lane & 15, l4 = lane >> 4;
  const int h = blockIdx.y;
  const int q0 = blockIdx.x * 64;
  const int r_st = t >> 3, slot = t & 7;

  const int qrow = q0 + w * 16 + l15;
  bf16x8 qa0 = *reinterpret_cast<const bf16x8*>(QT + (size_t)qrow * 512 + h * 64 + l4 * 8);
  bf16x8 qa1 = *reinterpret_cast<const bf16x8*>(QT + (size_t)qrow * 512 + h * 64 + 32 + l4 * 8);

  f32x4 o_acc[4] = {};
  float m_run = -1e30f, l_run = 0.f;
  u16* pw = pbuf[w];
  const int swp = (l15 & 7) << 4;

  auto stage = [&](int tile, int b) {
#pragma unroll
    for (int q = 0; q < 2; ++q) {
      int row = q * 32 + r_st;
      int so = (slot ^ (row & 7)) * 8;
      gload_lds16(KT + (size_t)(tile * 64 + row) * 512 + h * 64 + so,
                  (char*)kbuf[b] + q * 4096 + w * 1024);
      gload_lds16(V + (size_t)(h * 64 + row) * 4096 + tile * 64 + so,
                  (char*)vbuf[b] + q * 4096 + w * 1024);
    }
  };

  stage(0, 0);
  __syncthreads();

  for (int kt = 0; kt < 64; ++kt) {
    const int cur = kt & 1;
    if (kt < 63) stage(kt + 1, cur ^ 1);

    // swapped QK^T: s[n][r] = S[q=l15][ctx = n*16 + l4*4 + r]
    f32x4 s[4];
#pragma unroll
    for (int n = 0; n < 4; ++n) {
      int row = n * 16 + l15;
      int sw = (row & 7) << 4;
      bf16x8 kb0 = *reinterpret_cast<const bf16x8*>((const char*)kbuf[cur] + row * 128 + ((l4 * 16) ^ sw));
      bf16x8 kb1 = *reinterpret_cast<const bf16x8*>((const char*)kbuf[cur] + row * 128 + ((l4 * 16 + 64) ^ sw));
      f32x4 z = {};
      z = __builtin_amdgcn_mfma_f32_16x16x32_bf16(kb0, qa0, z, 0, 0, 0);
      z = __builtin_amdgcn_mfma_f32_16x16x32_bf16(kb1, qa1, z, 0, 0, 0);
      s[n] = z;
    }

    // in-lane row max (q = l15), 2 cross-lane steps over l4
    float mx = s[0][0];
#pragma unroll
    for (int n = 0; n < 4; ++n)
#pragma unroll
      for (int r = 0; r < 4; ++r) mx = fmaxf(mx, s[n][r]);
    mx = fmaxf(mx, __shfl_xor(mx, 16, 64));
    mx = fmaxf(mx, __shfl_xor(mx, 32, 64));

    if (__any(mx > m_run + 8.f)) {  // defer-max (T13)
      float mn = fmaxf(m_run, mx);
      float al = __expf(m_run - mn);
      m_run = mn;
      l_run *= al;
      float ar0 = __shfl(al, l4 * 4 + 0, 64);
      float ar1 = __shfl(al, l4 * 4 + 1, 64);
      float ar2 = __shfl(al, l4 * 4 + 2, 64);
      float ar3 = __shfl(al, l4 * 4 + 3, 64);
#pragma unroll
      for (int dt = 0; dt < 4; ++dt) {
        o_acc[dt][0] *= ar0; o_acc[dt][1] *= ar1;
        o_acc[dt][2] *= ar2; o_acc[dt][3] *= ar3;
      }
    }

    float part = 0.f;
#pragma unroll
    for (int n = 0; n < 4; ++n)
#pragma unroll
      for (int r = 0; r < 4; ++r) {
        float p = __expf(s[n][r] - m_run);
        s[n][r] = p;
        part += p;
      }
    l_run += part;

    // P -> per-wave LDS [q=l15][ctx], packed b64 writes
#pragma unroll
    for (int n = 0; n < 4; ++n) {
      uint2 u;
      u.x = cvtpk(s[n][0], s[n][1]);
      u.y = cvtpk(s[n][2], s[n][3]);
      int off = (l15 * 128 + n * 32 + l4 * 8) ^ swp;
      *reinterpret_cast<uint2*>((char*)pw + off) = u;
    }

    // O += P V
#pragma unroll
    for (int kk = 0; kk < 2; ++kk) {
      bf16x8 pa = *reinterpret_cast<const bf16x8*>((const char*)pw + l15 * 128 + ((l4 * 16 + kk * 64) ^ swp));
#pragma unroll
      for (int dt = 0; dt < 4; ++dt) {
        int drow = dt * 16 + l15;
        bf16x8 vb = *reinterpret_cast<const bf16x8*>((const char*)vbuf[cur] + drow * 128 +
                                                     ((l4 * 16 + kk * 64) ^ ((drow & 7) << 4)));
        o_acc[dt] = __builtin_amdgcn_mfma_f32_16x16x32_bf16(pa, vb, o_acc[dt], 0, 0, 0);
      }
    }
    __syncthreads();
  }

  l_run += __shfl_xor(l_run, 16, 64);
  l_run += __shfl_xor(l_run, 32, 64);
  float inv[4];
#pragma unroll
  for (int r = 0; r < 4; ++r) inv[r] = 1.0f / __shfl(l_run, l4 * 4 + r, 64);

#pragma unroll
  for (int r = 0; r < 4; ++r) {
    int orow = q0 + w * 16 + l4 * 4 + r;
#pragma unroll
    for (int dt = 0; dt < 4; ++dt)
      Ot[(size_t)orow * 512 + h * 64 + dt * 16 + l15] = f2bf(o_acc[dt][r] * inv[r]);
  }
}

// ---------------- host launch -------------------------------------------------
extern "C" void kernel_launch(void* const* d_in, const int* in_sizes, int n_in,
                              void* d_out, int out_size, void* d_ws, size_t ws_size,
                              hipStream_t stream) {
  const float* x    = (const float*)d_in[0];
  const float* ctx  = (const float*)d_in[1];
  const float* gn_w = (const float*)d_in[2];
  const float* gn_b = (const float*)d_in[3];
  const float* wq   = (const float*)d_in[4];
  const float* bq   = (const float*)d_in[5];
  const float* wk   = (const float*)d_in[6];
  const float* bk   = (const float*)d_in[7];
  const float* wv   = (const float*)d_in[8];
  const float* bv   = (const float*)d_in[9];
  const float* wo   = (const float*)d_in[10];
  const float* bo   = (const float*)d_in[11];

  char* ws = (char*)d_ws;
  float* sc   = (float*)ws;
  float* sh   = (float*)(ws + 2048);
  u16* wqB    = (u16*)(ws + 4096);
  u16* wkB    = wqB + 512 * 512;
  u16* wvB    = wkB + 512 * 768;
  u16* woB    = wvB + 512 * 768;
  u16* hT     = woB + 512 * 512;                  // [4096][512]
  u16* ctxT   = hT + 4096 * 512;                  // [4096][768]
  u16* QT     = ctxT + 4096 * 768;                // [4096][512]
  u16* KT     = QT + 4096 * 512;                  // [4096][512]
  u16* Vb     = KT + 4096 * 512;                  // [512][4096]
  u16* OtT    = Vb + (size_t)512 * 4096;          // [4096][512]

  cvt_bf16<<<256, 256, 0, stream>>>(wq, wqB, 512 * 512);
  cvt_bf16<<<384, 256, 0, stream>>>(wk, wkB, 512 * 768);
  cvt_bf16<<<384, 256, 0, stream>>>(wv, wvB, 512 * 768);
  cvt_bf16<<<256, 256, 0, stream>>>(wo, woB, 512 * 512);

  gn_stats<<<32, 256, 0, stream>>>(x, gn_w, gn_b, sc, sh);
  transpose_norm<<<dim3(64, 8), 256, 0, stream>>>(x, hT, 512, sc, sh);
  transpose_norm<<<dim3(64, 12), 256, 0, stream>>>(ctx, ctxT, 768, nullptr, nullptr);

  gemm_nt<64, 1, true, false><<<dim3(8, 32), 256, 0, stream>>>(hT, wqB, QT, bq, nullptr, 4096, 512, 512, 0.125f);
  gemm_nt<64, 1, true, false><<<dim3(8, 32), 256, 0, stream>>>(ctxT, wkB, KT, bk, nullptr, 4096, 512, 768, 1.0f);
  gemm_nt<64, 0, true, false><<<dim3(64, 4), 256, 0, stream>>>(wvB, ctxT, Vb, bv, nullptr, 512, 4096, 768, 1.0f);

  attn_kernel<<<dim3(64, 8), 256, 0, stream>>>(QT, KT, Vb, OtT);

  gemm_nt<64, 0, false, true><<<dim3(64, 4), 256, 0, stream>>>(woB, OtT, d_out, bo, x, 512, 4096, 512, 1.0f);
}

// Round 3
// 144.053 us; speedup vs baseline: 1.7085x; 1.1892x over previous
//
#include <hip/hip_runtime.h>
#include <cstdint>
#include <cstddef>

typedef __attribute__((ext_vector_type(8))) short bf16x8;
typedef __attribute__((ext_vector_type(4))) float f32x4;
typedef unsigned short u16;

__device__ inline u16 f2bf(float x) {
  uint32_t u = __builtin_bit_cast(uint32_t, x);
  u += 0x7FFFu + ((u >> 16) & 1u);
  return (u16)(u >> 16);
}
__device__ inline float bf2f(u16 v) {
  return __builtin_bit_cast(float, (uint32_t)v << 16);
}
__device__ inline uint32_t cvtpk(float a, float b) {
  uint32_t r;
  asm("v_cvt_pk_bf16_f32 %0, %1, %2" : "=v"(r) : "v"(a), "v"(b));
  return r;
}
__device__ inline void gload_lds16(const void* g, void* l) {
  __builtin_amdgcn_global_load_lds(
      (const __attribute__((address_space(1))) char*)g,
      (__attribute__((address_space(3))) char*)l, 16, 0, 0);
}

// ---------------- merged weight f32 -> bf16 convert (4 tensors, 1 launch) ----
__global__ __launch_bounds__(256) void cvt_all(const float* __restrict__ s0, u16* __restrict__ d0,
                                               const float* __restrict__ s1, u16* __restrict__ d1,
                                               const float* __restrict__ s2, u16* __restrict__ d2,
                                               const float* __restrict__ s3, u16* __restrict__ d3) {
  int b = blockIdx.x;
  const float* s; u16* d; int off;
  if (b < 256)       { s = s0; d = d0; off = b; }
  else if (b < 640)  { s = s1; d = d1; off = b - 256; }
  else if (b < 1024) { s = s2; d = d2; off = b - 640; }
  else               { s = s3; d = d3; off = b - 1024; }
  int i = (off * 256 + threadIdx.x) * 4;
  float4 v = *reinterpret_cast<const float4*>(s + i);
  u16 o[4] = {f2bf(v.x), f2bf(v.y), f2bf(v.z), f2bf(v.w)};
  *reinterpret_cast<uint2*>(d + i) = *reinterpret_cast<const uint2*>(o);
}

// ---------------- GroupNorm stats: per-channel scale/shift ----------------
__global__ __launch_bounds__(256) void gn_stats(const float* __restrict__ x,
                                                const float* __restrict__ w,
                                                const float* __restrict__ b,
                                                float* __restrict__ sc,
                                                float* __restrict__ sh) {
  __shared__ float rs[4], rss[4];
  int g = blockIdx.x;
  const float* base = x + (size_t)g * 16 * 4096;
  int t = threadIdx.x;
  float s = 0.f, ss = 0.f;
  for (int i = t * 4; i < 65536; i += 1024) {
    float4 v = *reinterpret_cast<const float4*>(base + i);
    s += v.x + v.y + v.z + v.w;
    ss += v.x * v.x + v.y * v.y + v.z * v.z + v.w * v.w;
  }
  for (int d = 32; d; d >>= 1) {
    s += __shfl_down(s, d, 64);
    ss += __shfl_down(ss, d, 64);
  }
  int wid = t >> 6;
  if ((t & 63) == 0) { rs[wid] = s; rss[wid] = ss; }
  __syncthreads();
  if (t < 16) {
    float S = rs[0] + rs[1] + rs[2] + rs[3];
    float SS = rss[0] + rss[1] + rss[2] + rss[3];
    float mu = S / 65536.f;
    float var = SS / 65536.f - mu * mu;
    float rstd = rsqrtf(var + 1e-5f);
    int c = g * 16 + t;
    sc[c] = w[c] * rstd;
    sh[c] = b[c] - mu * rstd * w[c];
  }
}

// ---------------- normalize (optional) + transpose to token-major bf16 ------
__global__ __launch_bounds__(256) void transpose_norm(const float* __restrict__ in,
                                                      u16* __restrict__ out, int C,
                                                      const float* __restrict__ sc,
                                                      const float* __restrict__ sh) {
  __shared__ float tile[64][65];
  int p0 = blockIdx.x * 64, c0 = blockIdx.y * 64;
  int t = threadIdx.x;
  int cl = t >> 4, pl = (t & 15) * 4;
#pragma unroll
  for (int rep = 0; rep < 4; ++rep) {
    int c = cl + rep * 16;
    float4 v = *reinterpret_cast<const float4*>(in + (size_t)(c0 + c) * 4096 + p0 + pl);
    float s = 1.f, f = 0.f;
    if (sc) { s = sc[c0 + c]; f = sh[c0 + c]; }
    tile[c][pl + 0] = v.x * s + f;
    tile[c][pl + 1] = v.y * s + f;
    tile[c][pl + 2] = v.z * s + f;
    tile[c][pl + 3] = v.w * s + f;
  }
  __syncthreads();
#pragma unroll
  for (int rep = 0; rep < 16; ++rep) {
    int idx = rep * 256 + t;
    int pw = idx >> 6, cw = idx & 63;
    out[(size_t)(p0 + pw) * C + c0 + cw] = f2bf(tile[cw][pw]);
  }
}

// ---------------- NT GEMM body: D[i][j] = sum_k A[i][k]*B[j][k] --------------
// BM=128, BN=64. 3-buffer LDS, counted vmcnt, ONE barrier per K-step (T3+T4).
template <int BIAS_MODE, bool OUT_BF16, bool ADD_RES>
__device__ inline void gemm_body(const u16* __restrict__ A, const u16* __restrict__ B,
                                 void* __restrict__ Dv,
                                 const float* __restrict__ bias,
                                 const float* __restrict__ res,
                                 int Rb, int K, float oscale, int bx, int by) {
  __shared__ u16 aT[3][128 * 64];
  __shared__ u16 bT[3][64 * 64];
  const int t = threadIdx.x;
  const int lane = t & 63, w = t >> 6;
  const int wr = w >> 1, wc = w & 1;
  const int l15 = lane & 15, l4 = lane >> 4;
  const int i0 = by * 128, j0 = bx * 64;
  const int r_st = t >> 3, slot = t & 7;
  f32x4 acc[4][2] = {};

  auto stage = [&](int kt, int b) {
#pragma unroll
    for (int q = 0; q < 4; ++q) {
      int row = q * 32 + r_st;
      int koff = kt + ((slot ^ (row & 7)) * 8);
      gload_lds16(A + (size_t)(i0 + row) * K + koff, (char*)aT[b] + q * 4096 + w * 1024);
    }
#pragma unroll
    for (int q = 0; q < 2; ++q) {
      int row = q * 32 + r_st;
      int koff = kt + ((slot ^ (row & 7)) * 8);
      gload_lds16(B + (size_t)(j0 + row) * K + koff, (char*)bT[b] + q * 4096 + w * 1024);
    }
  };

  const int nt = K / 64;       // >= 8
  stage(0, 0);
  stage(64, 1);

  for (int tt = 0; tt < nt; ++tt) {
    const int cur = tt % 3;
    // tile tt ready (its 6 loads are oldest beyond the newest 6); keep tt+1 in flight
    if (tt + 1 < nt) asm volatile("s_waitcnt vmcnt(6)\n\ts_barrier" ::: "memory");
    else             asm volatile("s_waitcnt vmcnt(0)\n\ts_barrier" ::: "memory");
    if (tt + 2 < nt) stage((tt + 2) * 64, (tt + 2) % 3);

#pragma unroll
    for (int kk = 0; kk < 2; ++kk) {
      bf16x8 af[4], bfr[2];
#pragma unroll
      for (int m = 0; m < 4; ++m) {
        int row = wr * 64 + m * 16 + l15;
        int off = row * 128 + ((l4 * 16 + kk * 64) ^ ((row & 7) << 4));
        af[m] = *reinterpret_cast<const bf16x8*>((const char*)aT[cur] + off);
      }
#pragma unroll
      for (int n = 0; n < 2; ++n) {
        int row = wc * 32 + n * 16 + l15;
        int off = row * 128 + ((l4 * 16 + kk * 64) ^ ((row & 7) << 4));
        bfr[n] = *reinterpret_cast<const bf16x8*>((const char*)bT[cur] + off);
      }
#pragma unroll
      for (int m = 0; m < 4; ++m)
#pragma unroll
        for (int n = 0; n < 2; ++n)
          acc[m][n] = __builtin_amdgcn_mfma_f32_16x16x32_bf16(af[m], bfr[n], acc[m][n], 0, 0, 0);
    }
  }

#pragma unroll
  for (int m = 0; m < 4; ++m) {
    int ib = i0 + wr * 64 + m * 16 + l4 * 4;
#pragma unroll
    for (int n = 0; n < 2; ++n) {
      int j = j0 + wc * 32 + n * 16 + l15;
#pragma unroll
      for (int r = 0; r < 4; ++r) {
        int i = ib + r;
        float v = acc[m][n][r];
        if (BIAS_MODE == 0) v += bias[i];
        else v += bias[j];
        v *= oscale;
        if (ADD_RES) v += res[(size_t)i * Rb + j];
        if (OUT_BF16)
          ((u16*)Dv)[(size_t)i * Rb + j] = f2bf(v);
        else
          ((float*)Dv)[(size_t)i * Rb + j] = v;
      }
    }
  }
}

// merged Q+K projection: z=0 -> Q (K=512, scale 1/8), z=1 -> K (K=768)
__global__ __launch_bounds__(256) void gemm_qk(const u16* __restrict__ hT, const u16* __restrict__ ctxT,
                                               const u16* __restrict__ wqB, const u16* __restrict__ wkB,
                                               u16* __restrict__ QT, u16* __restrict__ KT,
                                               const float* __restrict__ bq, const float* __restrict__ bk) {
  if (blockIdx.z == 0)
    gemm_body<1, true, false>(hT, wqB, QT, bq, nullptr, 512, 512, 0.125f, blockIdx.x, blockIdx.y);
  else
    gemm_body<1, true, false>(ctxT, wkB, KT, bk, nullptr, 512, 768, 1.0f, blockIdx.x, blockIdx.y);
}

template <int BIAS_MODE, bool OUT_BF16, bool ADD_RES>
__global__ __launch_bounds__(256) void gemm_nt(const u16* __restrict__ A, const u16* __restrict__ B,
                                               void* __restrict__ Dv,
                                               const float* __restrict__ bias,
                                               const float* __restrict__ res,
                                               int Rb, int K, float oscale) {
  gemm_body<BIAS_MODE, OUT_BF16, ADD_RES>(A, B, Dv, bias, res, Rb, K, oscale, blockIdx.x, blockIdx.y);
}

// ---------------- flash attention, KV-split x2 -------------------------------
// QT,KT: bf16 [4096][512] (Q pre-scaled). V: bf16 [512][4096] d-major.
// Opart: bf16 [2][4096][512] unnormalized; Mb,Lb: f32 [2][8][4096].
__global__ __launch_bounds__(256) void attn_kernel(const u16* __restrict__ QT,
                                                   const u16* __restrict__ KT,
                                                   const u16* __restrict__ V,
                                                   u16* __restrict__ Opart,
                                                   float* __restrict__ Mb,
                                                   float* __restrict__ Lb) {
  __shared__ u16 kbuf[2][64 * 64];
  __shared__ u16 vbuf[2][64 * 64];
  __shared__ u16 pbuf[4][16 * 64];
  const int t = threadIdx.x;
  const int lane = t & 63, w = t >> 6;
  const int l15 = lane & 15, l4 = lane >> 4;
  const int h = blockIdx.y;
  const int q0 = blockIdx.x * 64;
  const int z = blockIdx.z;
  const int tile0 = z * 32;
  const int r_st = t >> 3, slot = t & 7;

  const int qrow = q0 + w * 16 + l15;
  bf16x8 qa0 = *reinterpret_cast<const bf16x8*>(QT + (size_t)qrow * 512 + h * 64 + l4 * 8);
  bf16x8 qa1 = *reinterpret_cast<const bf16x8*>(QT + (size_t)qrow * 512 + h * 64 + 32 + l4 * 8);

  f32x4 o_acc[4] = {};
  float m_run = -1e30f, l_run = 0.f;
  u16* pw = pbuf[w];
  const int swp = (l15 & 7) << 4;

  auto stage = [&](int tile, int b) {
#pragma unroll
    for (int q = 0; q < 2; ++q) {
      int row = q * 32 + r_st;
      int so = (slot ^ (row & 7)) * 8;
      gload_lds16(KT + (size_t)(tile * 64 + row) * 512 + h * 64 + so,
                  (char*)kbuf[b] + q * 4096 + w * 1024);
      gload_lds16(V + (size_t)(h * 64 + row) * 4096 + tile * 64 + so,
                  (char*)vbuf[b] + q * 4096 + w * 1024);
    }
  };

  stage(tile0, 0);
  __syncthreads();

  for (int kt = 0; kt < 32; ++kt) {
    const int cur = kt & 1;
    if (kt < 31) stage(tile0 + kt + 1, cur ^ 1);

    // swapped QK^T: s[n][r] = S[q=l15][ctx = n*16 + l4*4 + r]
    f32x4 s[4];
#pragma unroll
    for (int n = 0; n < 4; ++n) {
      int row = n * 16 + l15;
      int sw = (row & 7) << 4;
      bf16x8 kb0 = *reinterpret_cast<const bf16x8*>((const char*)kbuf[cur] + row * 128 + ((l4 * 16) ^ sw));
      bf16x8 kb1 = *reinterpret_cast<const bf16x8*>((const char*)kbuf[cur] + row * 128 + ((l4 * 16 + 64) ^ sw));
      f32x4 z4 = {};
      z4 = __builtin_amdgcn_mfma_f32_16x16x32_bf16(kb0, qa0, z4, 0, 0, 0);
      z4 = __builtin_amdgcn_mfma_f32_16x16x32_bf16(kb1, qa1, z4, 0, 0, 0);
      s[n] = z4;
    }

    float mx = s[0][0];
#pragma unroll
    for (int n = 0; n < 4; ++n)
#pragma unroll
      for (int r = 0; r < 4; ++r) mx = fmaxf(mx, s[n][r]);
    mx = fmaxf(mx, __shfl_xor(mx, 16, 64));
    mx = fmaxf(mx, __shfl_xor(mx, 32, 64));

    if (__any(mx > m_run + 8.f)) {  // defer-max (T13)
      float mn = fmaxf(m_run, mx);
      float al = __expf(m_run - mn);
      m_run = mn;
      l_run *= al;
      float ar0 = __shfl(al, l4 * 4 + 0, 64);
      float ar1 = __shfl(al, l4 * 4 + 1, 64);
      float ar2 = __shfl(al, l4 * 4 + 2, 64);
      float ar3 = __shfl(al, l4 * 4 + 3, 64);
#pragma unroll
      for (int dt = 0; dt < 4; ++dt) {
        o_acc[dt][0] *= ar0; o_acc[dt][1] *= ar1;
        o_acc[dt][2] *= ar2; o_acc[dt][3] *= ar3;
      }
    }

    float part = 0.f;
#pragma unroll
    for (int n = 0; n < 4; ++n)
#pragma unroll
      for (int r = 0; r < 4; ++r) {
        float p = __expf(s[n][r] - m_run);
        s[n][r] = p;
        part += p;
      }
    l_run += part;

#pragma unroll
    for (int n = 0; n < 4; ++n) {
      uint2 u;
      u.x = cvtpk(s[n][0], s[n][1]);
      u.y = cvtpk(s[n][2], s[n][3]);
      int off = (l15 * 128 + n * 32 + l4 * 8) ^ swp;
      *reinterpret_cast<uint2*>((char*)pw + off) = u;
    }

#pragma unroll
    for (int kk = 0; kk < 2; ++kk) {
      bf16x8 pa = *reinterpret_cast<const bf16x8*>((const char*)pw + l15 * 128 + ((l4 * 16 + kk * 64) ^ swp));
#pragma unroll
      for (int dt = 0; dt < 4; ++dt) {
        int drow = dt * 16 + l15;
        bf16x8 vb = *reinterpret_cast<const bf16x8*>((const char*)vbuf[cur] + drow * 128 +
                                                     ((l4 * 16 + kk * 64) ^ ((drow & 7) << 4)));
        o_acc[dt] = __builtin_amdgcn_mfma_f32_16x16x32_bf16(pa, vb, o_acc[dt], 0, 0, 0);
      }
    }
    __syncthreads();
  }

  l_run += __shfl_xor(l_run, 16, 64);
  l_run += __shfl_xor(l_run, 32, 64);

  // unnormalized bf16 partials + (m,l)
#pragma unroll
  for (int r = 0; r < 4; ++r) {
    int orow = q0 + w * 16 + l4 * 4 + r;
#pragma unroll
    for (int dt = 0; dt < 4; ++dt)
      Opart[((size_t)z * 4096 + orow) * 512 + h * 64 + dt * 16 + l15] = f2bf(o_acc[dt][r]);
  }
  if (l4 == 0) {
    int q = q0 + w * 16 + l15;
    Mb[z * 32768 + h * 4096 + q] = m_run;
    Lb[z * 32768 + h * 4096 + q] = l_run;
  }
}

// ---------------- combine two KV-split partials ------------------------------
__global__ __launch_bounds__(256) void attn_combine(const u16* __restrict__ Opart,
                                                    const float* __restrict__ Mb,
                                                    const float* __restrict__ Lb,
                                                    u16* __restrict__ OtT) {
  int idx = blockIdx.x * 256 + threadIdx.x;   // one per 4 channels
  int q = idx >> 7;
  int c = (idx & 127) * 4;
  int h = c >> 6;
  float m0 = Mb[h * 4096 + q], m1 = Mb[32768 + h * 4096 + q];
  float l0 = Lb[h * 4096 + q], l1 = Lb[32768 + h * 4096 + q];
  float M = fmaxf(m0, m1);
  float w0 = __expf(m0 - M), w1 = __expf(m1 - M);
  float inv = 1.f / (w0 * l0 + w1 * l1);
  w0 *= inv; w1 *= inv;
  uint2 a = *reinterpret_cast<const uint2*>(Opart + (size_t)q * 512 + c);
  uint2 b = *reinterpret_cast<const uint2*>(Opart + (size_t)4096 * 512 + (size_t)q * 512 + c);
  u16 o[4];
  o[0] = f2bf(bf2f((u16)(a.x & 0xFFFF)) * w0 + bf2f((u16)(b.x & 0xFFFF)) * w1);
  o[1] = f2bf(bf2f((u16)(a.x >> 16)) * w0 + bf2f((u16)(b.x >> 16)) * w1);
  o[2] = f2bf(bf2f((u16)(a.y & 0xFFFF)) * w0 + bf2f((u16)(b.y & 0xFFFF)) * w1);
  o[3] = f2bf(bf2f((u16)(a.y >> 16)) * w0 + bf2f((u16)(b.y >> 16)) * w1);
  *reinterpret_cast<uint2*>(OtT + (size_t)q * 512 + c) = *reinterpret_cast<const uint2*>(o);
}

// ---------------- host launch -------------------------------------------------
extern "C" void kernel_launch(void* const* d_in, const int* in_sizes, int n_in,
                              void* d_out, int out_size, void* d_ws, size_t ws_size,
                              hipStream_t stream) {
  const float* x    = (const float*)d_in[0];
  const float* ctx  = (const float*)d_in[1];
  const float* gn_w = (const float*)d_in[2];
  const float* gn_b = (const float*)d_in[3];
  const float* wq   = (const float*)d_in[4];
  const float* bq   = (const float*)d_in[5];
  const float* wk   = (const float*)d_in[6];
  const float* bk   = (const float*)d_in[7];
  const float* wv   = (const float*)d_in[8];
  const float* bv   = (const float*)d_in[9];
  const float* wo   = (const float*)d_in[10];
  const float* bo   = (const float*)d_in[11];

  char* ws = (char*)d_ws;
  float* sc   = (float*)ws;
  float* sh   = (float*)(ws + 2048);
  u16* wqB    = (u16*)(ws + 4096);
  u16* wkB    = wqB + 512 * 512;
  u16* wvB    = wkB + 512 * 768;
  u16* woB    = wvB + 512 * 768;
  u16* hT     = woB + 512 * 512;                  // [4096][512]
  u16* ctxT   = hT + 4096 * 512;                  // [4096][768]
  u16* QT     = ctxT + 4096 * 768;                // [4096][512]
  u16* KT     = QT + 4096 * 512;                  // [4096][512]
  u16* Vb     = KT + 4096 * 512;                  // [512][4096]
  u16* OtT    = Vb + (size_t)512 * 4096;          // [4096][512]
  float* Mb   = (float*)(OtT + (size_t)4096 * 512);  // [2][8][4096]
  float* Lb   = Mb + 65536;
  u16* Opart  = hT;  // overlays hT + first 4MB of ctxT (dead by attn time)

  cvt_all<<<1280, 256, 0, stream>>>(wq, wqB, wk, wkB, wv, wvB, wo, woB);
  gn_stats<<<32, 256, 0, stream>>>(x, gn_w, gn_b, sc, sh);
  transpose_norm<<<dim3(64, 8), 256, 0, stream>>>(x, hT, 512, sc, sh);
  transpose_norm<<<dim3(64, 12), 256, 0, stream>>>(ctx, ctxT, 768, nullptr, nullptr);

  gemm_qk<<<dim3(8, 32, 2), 256, 0, stream>>>(hT, ctxT, wqB, wkB, QT, KT, bq, bk);
  gemm_nt<0, true, false><<<dim3(64, 4), 256, 0, stream>>>(wvB, ctxT, Vb, bv, nullptr, 4096, 768, 1.0f);

  attn_kernel<<<dim3(64, 8, 2), 256, 0, stream>>>(QT, KT, Vb, Opart, Mb, Lb);
  attn_combine<<<2048, 256, 0, stream>>>(Opart, Mb, Lb, OtT);

  gemm_nt<0, false, true><<<dim3(64, 4), 256, 0, stream>>>(woB, OtT, d_out, bo, x, 4096, 512, 1.0f);
}

// Round 5
// 130.925 us; speedup vs baseline: 1.8798x; 1.1003x over previous
//
#include <hip/hip_runtime.h>
#include <cstdint>
#include <cstddef>

typedef __attribute__((ext_vector_type(8))) short bf16x8;
typedef __attribute__((ext_vector_type(4))) float f32x4;
typedef unsigned short u16;

#define QSCALE (0.125f * 1.44269504088896f)  // fold softmax scale + log2e into Q

__device__ inline u16 f2bf(float x) {
  uint32_t u = __builtin_bit_cast(uint32_t, x);
  u += 0x7FFFu + ((u >> 16) & 1u);
  return (u16)(u >> 16);
}
__device__ inline float bf2f(u16 v) {
  return __builtin_bit_cast(float, (uint32_t)v << 16);
}
__device__ inline uint32_t cvtpk(float a, float b) {
  uint32_t r;
  asm("v_cvt_pk_bf16_f32 %0, %1, %2" : "=v"(r) : "v"(a), "v"(b));
  return r;
}
__device__ inline void gload_lds16(const void* g, void* l) {
  __builtin_amdgcn_global_load_lds(
      (const __attribute__((address_space(1))) char*)g,
      (__attribute__((address_space(3))) char*)l, 16, 0, 0);
}

// ---------------- GroupNorm partial sums (256 blocks, atomics) ---------------
__global__ __launch_bounds__(256) void gn_partial(const float* __restrict__ x,
                                                  float* __restrict__ gsum,
                                                  float* __restrict__ gsum2) {
  __shared__ float rs[4], rss[4];
  int b = blockIdx.x;
  int g = b >> 3, sl = b & 7;
  const float* base = x + (size_t)g * 65536 + sl * 8192;
  int t = threadIdx.x;
  float s = 0.f, ss = 0.f;
#pragma unroll
  for (int i = 0; i < 8; ++i) {
    float4 v = *reinterpret_cast<const float4*>(base + i * 1024 + t * 4);
    s += v.x + v.y + v.z + v.w;
    ss += v.x * v.x + v.y * v.y + v.z * v.z + v.w * v.w;
  }
  for (int d = 32; d; d >>= 1) {
    s += __shfl_down(s, d, 64);
    ss += __shfl_down(ss, d, 64);
  }
  int wid = t >> 6;
  if ((t & 63) == 0) { rs[wid] = s; rss[wid] = ss; }
  __syncthreads();
  if (t == 0) {
    atomicAdd(gsum + g, rs[0] + rs[1] + rs[2] + rs[3]);
    atomicAdd(gsum2 + g, rss[0] + rss[1] + rss[2] + rss[3]);
  }
}

// ---------------- prep: weight cvt + both transposes (one launch) ------------
// blocks [0,1280): cvt wq/wk/wv/wo; [1280,1792): x norm-transpose; [1792,2560): ctx transpose
__global__ __launch_bounds__(256) void prep(const float* __restrict__ wq, u16* __restrict__ wqB,
                                            const float* __restrict__ wk, u16* __restrict__ wkB,
                                            const float* __restrict__ wv, u16* __restrict__ wvB,
                                            const float* __restrict__ wo, u16* __restrict__ woB,
                                            const float* __restrict__ x, u16* __restrict__ hT,
                                            const float* __restrict__ ctx, u16* __restrict__ ctxT,
                                            const float* __restrict__ gnw, const float* __restrict__ gnb,
                                            const float* __restrict__ gsum, const float* __restrict__ gsum2) {
  int b = blockIdx.x;
  int t = threadIdx.x;
  if (b < 1280) {
    const float* s; u16* d; int off;
    if (b < 256)       { s = wq; d = wqB; off = b; }
    else if (b < 640)  { s = wk; d = wkB; off = b - 256; }
    else if (b < 1024) { s = wv; d = wvB; off = b - 640; }
    else               { s = wo; d = woB; off = b - 1024; }
    int i = (off * 256 + t) * 4;
    float4 v = *reinterpret_cast<const float4*>(s + i);
    u16 o[4] = {f2bf(v.x), f2bf(v.y), f2bf(v.z), f2bf(v.w)};
    *reinterpret_cast<uint2*>(d + i) = *reinterpret_cast<const uint2*>(o);
    return;
  }
  __shared__ float tile[64][65];
  const float* in; u16* out; int C, p0, c0;
  bool norm = false;
  if (b < 1792) {
    int idx = b - 1280;
    in = x; out = hT; C = 512; p0 = (idx & 63) * 64; c0 = (idx >> 6) * 64; norm = true;
  } else {
    int idx = b - 1792;
    in = ctx; out = ctxT; C = 768; p0 = (idx & 63) * 64; c0 = (idx >> 6) * 64;
  }
  int cl = t >> 4, pl = (t & 15) * 4;
#pragma unroll
  for (int rep = 0; rep < 4; ++rep) {
    int c = cl + rep * 16;
    float4 v = *reinterpret_cast<const float4*>(in + (size_t)(c0 + c) * 4096 + p0 + pl);
    float s = 1.f, f = 0.f;
    if (norm) {
      int g = (c0 + c) >> 4;
      float mu = gsum[g] * (1.f / 65536.f);
      float var = gsum2[g] * (1.f / 65536.f) - mu * mu;
      float rstd = rsqrtf(var + 1e-5f);
      s = gnw[c0 + c] * rstd;
      f = gnb[c0 + c] - mu * s;
    }
    tile[c][pl + 0] = v.x * s + f;
    tile[c][pl + 1] = v.y * s + f;
    tile[c][pl + 2] = v.z * s + f;
    tile[c][pl + 3] = v.w * s + f;
  }
  __syncthreads();
#pragma unroll
  for (int rep = 0; rep < 16; ++rep) {
    int idx = rep * 256 + t;
    int pw = idx >> 6, cw = idx & 63;
    out[(size_t)(p0 + pw) * C + c0 + cw] = f2bf(tile[cw][pw]);
  }
}

// ---------------- NT GEMM body: D[i][j] = sum_k A[i][k]*B[j][k] --------------
// BM=128, BN=64. 3-buffer LDS, counted vmcnt, ONE barrier per K-step (T3+T4).
template <int BIAS_MODE, bool OUT_BF16, bool ADD_RES>
__device__ inline void gemm_body(u16* __restrict__ aT, u16* __restrict__ bT,
                                 const u16* __restrict__ A, const u16* __restrict__ B,
                                 void* __restrict__ Dv,
                                 const float* __restrict__ bias,
                                 const float* __restrict__ res,
                                 int Rb, int K, float oscale, int bx, int by) {
  const int t = threadIdx.x;
  const int lane = t & 63, w = t >> 6;
  const int wr = w >> 1, wc = w & 1;
  const int l15 = lane & 15, l4 = lane >> 4;
  const int i0 = by * 128, j0 = bx * 64;
  const int r_st = t >> 3, slot = t & 7;
  f32x4 acc[4][2] = {};

  auto stage = [&](int kt, int b) {
#pragma unroll
    for (int q = 0; q < 4; ++q) {
      int row = q * 32 + r_st;
      int koff = kt + ((slot ^ (row & 7)) * 8);
      gload_lds16(A + (size_t)(i0 + row) * K + koff, (char*)aT + b * 16384 + q * 4096 + w * 1024);
    }
#pragma unroll
    for (int q = 0; q < 2; ++q) {
      int row = q * 32 + r_st;
      int koff = kt + ((slot ^ (row & 7)) * 8);
      gload_lds16(B + (size_t)(j0 + row) * K + koff, (char*)bT + b * 8192 + q * 4096 + w * 1024);
    }
  };

  const int nt = K / 64;
  stage(0, 0);
  stage(64, 1);

  for (int tt = 0; tt < nt; ++tt) {
    const int cur = tt % 3;
    if (tt + 1 < nt) asm volatile("s_waitcnt vmcnt(6)\n\ts_barrier" ::: "memory");
    else             asm volatile("s_waitcnt vmcnt(0)\n\ts_barrier" ::: "memory");
    if (tt + 2 < nt) stage((tt + 2) * 64, (tt + 2) % 3);

#pragma unroll
    for (int kk = 0; kk < 2; ++kk) {
      bf16x8 af[4], bfr[2];
#pragma unroll
      for (int m = 0; m < 4; ++m) {
        int row = wr * 64 + m * 16 + l15;
        int off = row * 128 + ((l4 * 16 + kk * 64) ^ ((row & 7) << 4));
        af[m] = *reinterpret_cast<const bf16x8*>((const char*)aT + cur * 16384 + off);
      }
#pragma unroll
      for (int n = 0; n < 2; ++n) {
        int row = wc * 32 + n * 16 + l15;
        int off = row * 128 + ((l4 * 16 + kk * 64) ^ ((row & 7) << 4));
        bfr[n] = *reinterpret_cast<const bf16x8*>((const char*)bT + cur * 8192 + off);
      }
#pragma unroll
      for (int m = 0; m < 4; ++m)
#pragma unroll
        for (int n = 0; n < 2; ++n)
          acc[m][n] = __builtin_amdgcn_mfma_f32_16x16x32_bf16(af[m], bfr[n], acc[m][n], 0, 0, 0);
    }
  }

#pragma unroll
  for (int m = 0; m < 4; ++m) {
    int ib = i0 + wr * 64 + m * 16 + l4 * 4;
#pragma unroll
    for (int n = 0; n < 2; ++n) {
      int j = j0 + wc * 32 + n * 16 + l15;
#pragma unroll
      for (int r = 0; r < 4; ++r) {
        int i = ib + r;
        float v = acc[m][n][r];
        if (BIAS_MODE == 0) v += bias[i];
        else v += bias[j];
        v *= oscale;
        if (ADD_RES) v += res[(size_t)i * Rb + j];
        if (OUT_BF16)
          ((u16*)Dv)[(size_t)i * Rb + j] = f2bf(v);
        else
          ((float*)Dv)[(size_t)i * Rb + j] = v;
      }
    }
  }
}

// merged Q+K+V projections, 1D grid of 768 blocks
__global__ __launch_bounds__(256) void gemm_all(const u16* __restrict__ hT, const u16* __restrict__ ctxT,
                                                const u16* __restrict__ wqB, const u16* __restrict__ wkB,
                                                const u16* __restrict__ wvB,
                                                u16* __restrict__ QT, u16* __restrict__ KT, u16* __restrict__ Vb,
                                                const float* __restrict__ bq, const float* __restrict__ bk,
                                                const float* __restrict__ bv) {
  __shared__ u16 aT[3][128 * 64];
  __shared__ u16 bT[3][64 * 64];
  int b = blockIdx.x;
  if (b < 256)
    gemm_body<1, true, false>(&aT[0][0], &bT[0][0], hT, wqB, QT, bq, nullptr, 512, 512, QSCALE, b & 7, b >> 3);
  else if (b < 512)
    gemm_body<1, true, false>(&aT[0][0], &bT[0][0], ctxT, wkB, KT, bk, nullptr, 512, 768, 1.0f, (b - 256) & 7, (b - 256) >> 3);
  else
    gemm_body<0, true, false>(&aT[0][0], &bT[0][0], wvB, ctxT, Vb, bv, nullptr, 4096, 768, 1.0f, (b - 512) & 63, (b - 512) >> 6);
}

// output projection + residual
__global__ __launch_bounds__(256) void gemm_proj(const u16* __restrict__ woB, const u16* __restrict__ OtT,
                                                 void* __restrict__ Dv, const float* __restrict__ bo,
                                                 const float* __restrict__ res) {
  __shared__ u16 aT[3][128 * 64];
  __shared__ u16 bT[3][64 * 64];
  gemm_body<0, false, true>(&aT[0][0], &bT[0][0], woB, OtT, Dv, bo, res, 4096, 512, 1.0f,
                            blockIdx.x & 63, blockIdx.x >> 6);
}

// ---------------- flash attention, KV-split x2, register-resident P ----------
// QT,KT: bf16 [4096][512] (Q pre-scaled by QSCALE). V: bf16 [512][4096] d-major.
// Opart: bf16 [2][4096][512] unnormalized; Mb,Lb: f32 [2][8][4096] (m in log2).
__global__ __launch_bounds__(256) void attn_kernel(const u16* __restrict__ QT,
                                                   const u16* __restrict__ KT,
                                                   const u16* __restrict__ V,
                                                   u16* __restrict__ Opart,
                                                   float* __restrict__ Mb,
                                                   float* __restrict__ Lb) {
  __shared__ u16 kbuf[2][64 * 64];
  __shared__ u16 vbuf[2][64 * 64];
  const int t = threadIdx.x;
  const int lane = t & 63, w = t >> 6;
  const int l15 = lane & 15, l4 = lane >> 4;
  // XCD swizzle: 128 consecutive blocks (2 heads) per XCD
  int bid = blockIdx.z * 512 + blockIdx.y * 64 + blockIdx.x;
  bid = (bid & 7) * 128 + (bid >> 3);
  const int z = bid >> 9;
  const int h = (bid >> 6) & 7;
  const int q0 = (bid & 63) * 64;
  const int tile0 = z * 32;
  const int r_st = t >> 3, slot = t & 7;

  const int qrow = q0 + w * 16 + l15;
  bf16x8 qa0 = *reinterpret_cast<const bf16x8*>(QT + (size_t)qrow * 512 + h * 64 + l4 * 8);
  bf16x8 qa1 = *reinterpret_cast<const bf16x8*>(QT + (size_t)qrow * 512 + h * 64 + 32 + l4 * 8);

  f32x4 o_acc[4] = {};
  float m_run = -1e30f, l_run = 0.f;
  const int vch0 = (l4 & 1) * 4 + (l4 >> 1);  // V chunk for kk=0 (kk=1: +2)

  auto stage = [&](int tile, int b) {
#pragma unroll
    for (int q = 0; q < 2; ++q) {
      int row = q * 32 + r_st;
      int so = (slot ^ (row & 7)) * 8;
      gload_lds16(KT + (size_t)(tile * 64 + row) * 512 + h * 64 + so,
                  (char*)kbuf[b] + q * 4096 + w * 1024);
      gload_lds16(V + (size_t)(h * 64 + row) * 4096 + tile * 64 + so,
                  (char*)vbuf[b] + q * 4096 + w * 1024);
    }
  };

  stage(tile0, 0);
  __syncthreads();

  for (int kt = 0; kt < 32; ++kt) {
    const int cur = kt & 1;
    if (kt < 31) stage(tile0 + kt + 1, cur ^ 1);

    // swapped QK^T: s[n][r] = S[q=l15][ctx = n*16 + l4*4 + r]  (log2 units)
    f32x4 s[4];
    __builtin_amdgcn_s_setprio(1);
#pragma unroll
    for (int n = 0; n < 4; ++n) {
      int row = n * 16 + l15;
      int sw = (row & 7) << 4;
      bf16x8 kb0 = *reinterpret_cast<const bf16x8*>((const char*)kbuf[cur] + row * 128 + ((l4 * 16) ^ sw));
      bf16x8 kb1 = *reinterpret_cast<const bf16x8*>((const char*)kbuf[cur] + row * 128 + ((l4 * 16 + 64) ^ sw));
      f32x4 z4 = {};
      z4 = __builtin_amdgcn_mfma_f32_16x16x32_bf16(kb0, qa0, z4, 0, 0, 0);
      z4 = __builtin_amdgcn_mfma_f32_16x16x32_bf16(kb1, qa1, z4, 0, 0, 0);
      s[n] = z4;
    }
    __builtin_amdgcn_s_setprio(0);

    // in-lane row max (max3-friendly tree), 2 cross-lane steps over l4
    float a0 = fmaxf(fmaxf(s[0][0], s[0][1]), s[0][2]);
    float a1 = fmaxf(fmaxf(s[0][3], s[1][0]), s[1][1]);
    float a2 = fmaxf(fmaxf(s[1][2], s[1][3]), s[2][0]);
    float a3 = fmaxf(fmaxf(s[2][1], s[2][2]), s[2][3]);
    float a4 = fmaxf(fmaxf(s[3][0], s[3][1]), s[3][2]);
    float mx = fmaxf(fmaxf(fmaxf(a0, a1), fmaxf(a2, a3)), fmaxf(a4, s[3][3]));
    mx = fmaxf(mx, __shfl_xor(mx, 16, 64));
    mx = fmaxf(mx, __shfl_xor(mx, 32, 64));

    if (__any(mx > m_run + 11.5437f)) {  // defer-max (T13), 8 nats in log2
      float mn = fmaxf(m_run, mx);
      float al = exp2f(m_run - mn);
      m_run = mn;
      l_run *= al;
      float ar0 = __shfl(al, l4 * 4 + 0, 64);
      float ar1 = __shfl(al, l4 * 4 + 1, 64);
      float ar2 = __shfl(al, l4 * 4 + 2, 64);
      float ar3 = __shfl(al, l4 * 4 + 3, 64);
#pragma unroll
      for (int dt = 0; dt < 4; ++dt) {
        o_acc[dt][0] *= ar0; o_acc[dt][1] *= ar1;
        o_acc[dt][2] *= ar2; o_acc[dt][3] *= ar3;
      }
    }

    float ps0 = 0.f, ps1 = 0.f, ps2 = 0.f, ps3 = 0.f;
#pragma unroll
    for (int n = 0; n < 4; ++n) {
      float p0 = exp2f(s[n][0] - m_run);
      float p1 = exp2f(s[n][1] - m_run);
      float p2 = exp2f(s[n][2] - m_run);
      float p3 = exp2f(s[n][3] - m_run);
      s[n][0] = p0; s[n][1] = p1; s[n][2] = p2; s[n][3] = p3;
      ps0 += p0; ps1 += p1; ps2 += p2; ps3 += p3;
    }
    l_run += (ps0 + ps1) + (ps2 + ps3);

    // P -> bf16 A-fragments fully in registers: 8 cvt_pk + 4 permlane16_swap.
    // u[n][h] = pair(ctx = n*16 + l4*4 + 2h); after swap(u[kk][h], u[kk+2][h]):
    //   first  = pa[kk] word h   (chunks: l4=0:{0,2} 1:{4,6} 2:{1,3} 3:{5,7})
    //   second = pa[kk] word 2+h
    uint32_t u00 = cvtpk(s[0][0], s[0][1]), u01 = cvtpk(s[0][2], s[0][3]);
    uint32_t u10 = cvtpk(s[1][0], s[1][1]), u11 = cvtpk(s[1][2], s[1][3]);
    uint32_t u20 = cvtpk(s[2][0], s[2][1]), u21 = cvtpk(s[2][2], s[2][3]);
    uint32_t u30 = cvtpk(s[3][0], s[3][1]), u31 = cvtpk(s[3][2], s[3][3]);
    asm volatile("v_permlane16_swap_b32 %0, %1" : "+v"(u00), "+v"(u20));
    asm volatile("v_permlane16_swap_b32 %0, %1" : "+v"(u01), "+v"(u21));
    asm volatile("v_permlane16_swap_b32 %0, %1" : "+v"(u10), "+v"(u30));
    asm volatile("v_permlane16_swap_b32 %0, %1" : "+v"(u11), "+v"(u31));
    int4 pa0i = {(int)u00, (int)u01, (int)u20, (int)u21};
    int4 pa1i = {(int)u10, (int)u11, (int)u30, (int)u31};
    bf16x8 pa0 = __builtin_bit_cast(bf16x8, pa0i);
    bf16x8 pa1 = __builtin_bit_cast(bf16x8, pa1i);

    // O += P V  (V fragment chunks follow sigma(l4,kk))
    __builtin_amdgcn_s_setprio(1);
#pragma unroll
    for (int dt = 0; dt < 4; ++dt) {
      int drow = dt * 16 + l15;
      int sw = (drow & 7) << 4;
      bf16x8 vb0 = *reinterpret_cast<const bf16x8*>((const char*)vbuf[cur] + drow * 128 + ((vch0 * 16) ^ sw));
      o_acc[dt] = __builtin_amdgcn_mfma_f32_16x16x32_bf16(pa0, vb0, o_acc[dt], 0, 0, 0);
      bf16x8 vb1 = *reinterpret_cast<const bf16x8*>((const char*)vbuf[cur] + drow * 128 + (((vch0 + 2) * 16) ^ sw));
      o_acc[dt] = __builtin_amdgcn_mfma_f32_16x16x32_bf16(pa1, vb1, o_acc[dt], 0, 0, 0);
    }
    __builtin_amdgcn_s_setprio(0);
    __syncthreads();
  }

  l_run += __shfl_xor(l_run, 16, 64);
  l_run += __shfl_xor(l_run, 32, 64);

#pragma unroll
  for (int r = 0; r < 4; ++r) {
    int orow = q0 + w * 16 + l4 * 4 + r;
#pragma unroll
    for (int dt = 0; dt < 4; ++dt)
      Opart[((size_t)z * 4096 + orow) * 512 + h * 64 + dt * 16 + l15] = f2bf(o_acc[dt][r]);
  }
  if (l4 == 0) {
    int q = q0 + w * 16 + l15;
    Mb[z * 32768 + h * 4096 + q] = m_run;
    Lb[z * 32768 + h * 4096 + q] = l_run;
  }
}

// ---------------- combine two KV-split partials ------------------------------
__global__ __launch_bounds__(256) void attn_combine(const u16* __restrict__ Opart,
                                                    const float* __restrict__ Mb,
                                                    const float* __restrict__ Lb,
                                                    u16* __restrict__ OtT) {
  int idx = blockIdx.x * 256 + threadIdx.x;
  int q = idx >> 7;
  int c = (idx & 127) * 4;
  int h = c >> 6;
  float m0 = Mb[h * 4096 + q], m1 = Mb[32768 + h * 4096 + q];
  float l0 = Lb[h * 4096 + q], l1 = Lb[32768 + h * 4096 + q];
  float M = fmaxf(m0, m1);
  float w0 = exp2f(m0 - M), w1 = exp2f(m1 - M);
  float inv = 1.f / (w0 * l0 + w1 * l1);
  w0 *= inv; w1 *= inv;
  uint2 a = *reinterpret_cast<const uint2*>(Opart + (size_t)q * 512 + c);
  uint2 b = *reinterpret_cast<const uint2*>(Opart + (size_t)4096 * 512 + (size_t)q * 512 + c);
  u16 o[4];
  o[0] = f2bf(bf2f((u16)(a.x & 0xFFFF)) * w0 + bf2f((u16)(b.x & 0xFFFF)) * w1);
  o[1] = f2bf(bf2f((u16)(a.x >> 16)) * w0 + bf2f((u16)(b.x >> 16)) * w1);
  o[2] = f2bf(bf2f((u16)(a.y & 0xFFFF)) * w0 + bf2f((u16)(b.y & 0xFFFF)) * w1);
  o[3] = f2bf(bf2f((u16)(a.y >> 16)) * w0 + bf2f((u16)(b.y >> 16)) * w1);
  *reinterpret_cast<uint2*>(OtT + (size_t)q * 512 + c) = *reinterpret_cast<const uint2*>(o);
}

// ---------------- host launch -------------------------------------------------
extern "C" void kernel_launch(void* const* d_in, const int* in_sizes, int n_in,
                              void* d_out, int out_size, void* d_ws, size_t ws_size,
                              hipStream_t stream) {
  const float* x    = (const float*)d_in[0];
  const float* ctx  = (const float*)d_in[1];
  const float* gn_w = (const float*)d_in[2];
  const float* gn_b = (const float*)d_in[3];
  const float* wq   = (const float*)d_in[4];
  const float* bq   = (const float*)d_in[5];
  const float* wk   = (const float*)d_in[6];
  const float* bk   = (const float*)d_in[7];
  const float* wv   = (const float*)d_in[8];
  const float* bv   = (const float*)d_in[9];
  const float* wo   = (const float*)d_in[10];
  const float* bo   = (const float*)d_in[11];

  char* ws = (char*)d_ws;
  float* gsum  = (float*)ws;                      // 32 f32
  float* gsum2 = gsum + 32;                       // 32 f32
  u16* wqB    = (u16*)(ws + 4096);
  u16* wkB    = wqB + 512 * 512;
  u16* wvB    = wkB + 512 * 768;
  u16* woB    = wvB + 512 * 768;
  u16* hT     = woB + 512 * 512;                  // [4096][512]
  u16* ctxT   = hT + 4096 * 512;                  // [4096][768]
  u16* QT     = ctxT + 4096 * 768;                // [4096][512]
  u16* KT     = QT + 4096 * 512;                  // [4096][512]
  u16* Vb     = KT + 4096 * 512;                  // [512][4096]
  u16* OtT    = Vb + (size_t)512 * 4096;          // [4096][512]
  float* Mb   = (float*)(OtT + (size_t)4096 * 512);  // [2][8][4096]
  float* Lb   = Mb + 65536;
  u16* Opart  = hT;  // overlays hT + first 4MB of ctxT (dead by attn time)

  (void)hipMemsetAsync(gsum, 0, 256, stream);
  gn_partial<<<256, 256, 0, stream>>>(x, gsum, gsum2);
  prep<<<2560, 256, 0, stream>>>(wq, wqB, wk, wkB, wv, wvB, wo, woB,
                                 x, hT, ctx, ctxT, gn_w, gn_b, gsum, gsum2);

  gemm_all<<<768, 256, 0, stream>>>(hT, ctxT, wqB, wkB, wvB, QT, KT, Vb, bq, bk, bv);

  attn_kernel<<<dim3(64, 8, 2), 256, 0, stream>>>(QT, KT, Vb, Opart, Mb, Lb);
  attn_combine<<<2048, 256, 0, stream>>>(Opart, Mb, Lb, OtT);

  gemm_proj<<<256, 256, 0, stream>>>(woB, OtT, (float*)d_out, bo, x);
}

// Round 6
// 129.191 us; speedup vs baseline: 1.9050x; 1.0134x over previous
//
#include <hip/hip_runtime.h>
#include <cstdint>
#include <cstddef>

typedef __attribute__((ext_vector_type(8))) short bf16x8;
typedef __attribute__((ext_vector_type(4))) float f32x4;
typedef unsigned short u16;

#define QSCALE (0.125f * 1.44269504088896f)  // fold softmax scale + log2e into Q

__device__ inline u16 f2bf(float x) {
  uint32_t u = __builtin_bit_cast(uint32_t, x);
  u += 0x7FFFu + ((u >> 16) & 1u);
  return (u16)(u >> 16);
}
__device__ inline float bf2f(u16 v) {
  return __builtin_bit_cast(float, (uint32_t)v << 16);
}
__device__ inline uint32_t cvtpk(float a, float b) {
  uint32_t r;
  asm("v_cvt_pk_bf16_f32 %0, %1, %2" : "=v"(r) : "v"(a), "v"(b));
  return r;
}
__device__ inline void gload_lds16(const void* g, void* l) {
  __builtin_amdgcn_global_load_lds(
      (const __attribute__((address_space(1))) char*)g,
      (__attribute__((address_space(3))) char*)l, 16, 0, 0);
}

// ---------------- GroupNorm partial sums (256 blocks, atomics) ---------------
__global__ __launch_bounds__(256) void gn_partial(const float* __restrict__ x,
                                                  float* __restrict__ gsum,
                                                  float* __restrict__ gsum2) {
  __shared__ float rs[4], rss[4];
  int b = blockIdx.x;
  int g = b >> 3, sl = b & 7;
  const float* base = x + (size_t)g * 65536 + sl * 8192;
  int t = threadIdx.x;
  float s = 0.f, ss = 0.f;
#pragma unroll
  for (int i = 0; i < 8; ++i) {
    float4 v = *reinterpret_cast<const float4*>(base + i * 1024 + t * 4);
    s += v.x + v.y + v.z + v.w;
    ss += v.x * v.x + v.y * v.y + v.z * v.z + v.w * v.w;
  }
  for (int d = 32; d; d >>= 1) {
    s += __shfl_down(s, d, 64);
    ss += __shfl_down(ss, d, 64);
  }
  int wid = t >> 6;
  if ((t & 63) == 0) { rs[wid] = s; rss[wid] = ss; }
  __syncthreads();
  if (t == 0) {
    atomicAdd(gsum + g, rs[0] + rs[1] + rs[2] + rs[3]);
    atomicAdd(gsum2 + g, rss[0] + rss[1] + rss[2] + rss[3]);
  }
}

// ---------------- prep: weight cvt + both transposes (one launch) ------------
__global__ __launch_bounds__(256) void prep(const float* __restrict__ wq, u16* __restrict__ wqB,
                                            const float* __restrict__ wk, u16* __restrict__ wkB,
                                            const float* __restrict__ wv, u16* __restrict__ wvB,
                                            const float* __restrict__ wo, u16* __restrict__ woB,
                                            const float* __restrict__ x, u16* __restrict__ hT,
                                            const float* __restrict__ ctx, u16* __restrict__ ctxT,
                                            const float* __restrict__ gnw, const float* __restrict__ gnb,
                                            const float* __restrict__ gsum, const float* __restrict__ gsum2) {
  int b = blockIdx.x;
  int t = threadIdx.x;
  if (b < 1280) {
    const float* s; u16* d; int off;
    if (b < 256)       { s = wq; d = wqB; off = b; }
    else if (b < 640)  { s = wk; d = wkB; off = b - 256; }
    else if (b < 1024) { s = wv; d = wvB; off = b - 640; }
    else               { s = wo; d = woB; off = b - 1024; }
    int i = (off * 256 + t) * 4;
    float4 v = *reinterpret_cast<const float4*>(s + i);
    u16 o[4] = {f2bf(v.x), f2bf(v.y), f2bf(v.z), f2bf(v.w)};
    *reinterpret_cast<uint2*>(d + i) = *reinterpret_cast<const uint2*>(o);
    return;
  }
  __shared__ float tile[64][65];
  const float* in; u16* out; int C, p0, c0;
  bool norm = false;
  if (b < 1792) {
    int idx = b - 1280;
    in = x; out = hT; C = 512; p0 = (idx & 63) * 64; c0 = (idx >> 6) * 64; norm = true;
  } else {
    int idx = b - 1792;
    in = ctx; out = ctxT; C = 768; p0 = (idx & 63) * 64; c0 = (idx >> 6) * 64;
  }
  int cl = t >> 4, pl = (t & 15) * 4;
#pragma unroll
  for (int rep = 0; rep < 4; ++rep) {
    int c = cl + rep * 16;
    float4 v = *reinterpret_cast<const float4*>(in + (size_t)(c0 + c) * 4096 + p0 + pl);
    float s = 1.f, f = 0.f;
    if (norm) {
      int g = (c0 + c) >> 4;
      float mu = gsum[g] * (1.f / 65536.f);
      float var = gsum2[g] * (1.f / 65536.f) - mu * mu;
      float rstd = rsqrtf(var + 1e-5f);
      s = gnw[c0 + c] * rstd;
      f = gnb[c0 + c] - mu * s;
    }
    tile[c][pl + 0] = v.x * s + f;
    tile[c][pl + 1] = v.y * s + f;
    tile[c][pl + 2] = v.z * s + f;
    tile[c][pl + 3] = v.w * s + f;
  }
  __syncthreads();
#pragma unroll
  for (int rep = 0; rep < 16; ++rep) {
    int idx = rep * 256 + t;
    int pw = idx >> 6, cw = idx & 63;
    out[(size_t)(p0 + pw) * C + c0 + cw] = f2bf(tile[cw][pw]);
  }
}

// ---------------- NT GEMM body: D[i][j] = sum_k A[i][k]*B[j][k] --------------
// BM=128, BN=64. 3-buffer LDS, counted vmcnt, ONE barrier per K-step (T3+T4).
template <int BIAS_MODE, bool OUT_BF16, bool ADD_RES>
__device__ inline void gemm_body(u16* __restrict__ aT, u16* __restrict__ bT,
                                 const u16* __restrict__ A, const u16* __restrict__ B,
                                 void* __restrict__ Dv,
                                 const float* __restrict__ bias,
                                 const float* __restrict__ res,
                                 int Rb, int K, float oscale, int bx, int by) {
  const int t = threadIdx.x;
  const int lane = t & 63, w = t >> 6;
  const int wr = w >> 1, wc = w & 1;
  const int l15 = lane & 15, l4 = lane >> 4;
  const int i0 = by * 128, j0 = bx * 64;
  const int r_st = t >> 3, slot = t & 7;
  f32x4 acc[4][2] = {};

  auto stage = [&](int kt, int b) {
#pragma unroll
    for (int q = 0; q < 4; ++q) {
      int row = q * 32 + r_st;
      int koff = kt + ((slot ^ (row & 7)) * 8);
      gload_lds16(A + (size_t)(i0 + row) * K + koff, (char*)aT + b * 16384 + q * 4096 + w * 1024);
    }
#pragma unroll
    for (int q = 0; q < 2; ++q) {
      int row = q * 32 + r_st;
      int koff = kt + ((slot ^ (row & 7)) * 8);
      gload_lds16(B + (size_t)(j0 + row) * K + koff, (char*)bT + b * 8192 + q * 4096 + w * 1024);
    }
  };

  const int nt = K / 64;
  stage(0, 0);
  stage(64, 1);

  for (int tt = 0; tt < nt; ++tt) {
    const int cur = tt % 3;
    if (tt + 1 < nt) asm volatile("s_waitcnt vmcnt(6)\n\ts_barrier" ::: "memory");
    else             asm volatile("s_waitcnt vmcnt(0)\n\ts_barrier" ::: "memory");
    if (tt + 2 < nt) stage((tt + 2) * 64, (tt + 2) % 3);

#pragma unroll
    for (int kk = 0; kk < 2; ++kk) {
      bf16x8 af[4], bfr[2];
#pragma unroll
      for (int m = 0; m < 4; ++m) {
        int row = wr * 64 + m * 16 + l15;
        int off = row * 128 + ((l4 * 16 + kk * 64) ^ ((row & 7) << 4));
        af[m] = *reinterpret_cast<const bf16x8*>((const char*)aT + cur * 16384 + off);
      }
#pragma unroll
      for (int n = 0; n < 2; ++n) {
        int row = wc * 32 + n * 16 + l15;
        int off = row * 128 + ((l4 * 16 + kk * 64) ^ ((row & 7) << 4));
        bfr[n] = *reinterpret_cast<const bf16x8*>((const char*)bT + cur * 8192 + off);
      }
#pragma unroll
      for (int m = 0; m < 4; ++m)
#pragma unroll
        for (int n = 0; n < 2; ++n)
          acc[m][n] = __builtin_amdgcn_mfma_f32_16x16x32_bf16(af[m], bfr[n], acc[m][n], 0, 0, 0);
    }
  }

#pragma unroll
  for (int m = 0; m < 4; ++m) {
    int ib = i0 + wr * 64 + m * 16 + l4 * 4;
#pragma unroll
    for (int n = 0; n < 2; ++n) {
      int j = j0 + wc * 32 + n * 16 + l15;
#pragma unroll
      for (int r = 0; r < 4; ++r) {
        int i = ib + r;
        float v = acc[m][n][r];
        if (BIAS_MODE == 0) v += bias[i];
        else v += bias[j];
        v *= oscale;
        if (ADD_RES) v += res[(size_t)i * Rb + j];
        if (OUT_BF16)
          ((u16*)Dv)[(size_t)i * Rb + j] = f2bf(v);
        else
          ((float*)Dv)[(size_t)i * Rb + j] = v;
      }
    }
  }
}

// merged Q+K+V projections, 1D grid of 768 blocks
__global__ __launch_bounds__(256) void gemm_all(const u16* __restrict__ hT, const u16* __restrict__ ctxT,
                                                const u16* __restrict__ wqB, const u16* __restrict__ wkB,
                                                const u16* __restrict__ wvB,
                                                u16* __restrict__ QT, u16* __restrict__ KT, u16* __restrict__ Vb,
                                                const float* __restrict__ bq, const float* __restrict__ bk,
                                                const float* __restrict__ bv) {
  __shared__ u16 aT[3][128 * 64];
  __shared__ u16 bT[3][64 * 64];
  int b = blockIdx.x;
  if (b < 256)
    gemm_body<1, true, false>(&aT[0][0], &bT[0][0], hT, wqB, QT, bq, nullptr, 512, 512, QSCALE, b & 7, b >> 3);
  else if (b < 512)
    gemm_body<1, true, false>(&aT[0][0], &bT[0][0], ctxT, wkB, KT, bk, nullptr, 512, 768, 1.0f, (b - 256) & 7, (b - 256) >> 3);
  else
    gemm_body<0, true, false>(&aT[0][0], &bT[0][0], wvB, ctxT, Vb, bv, nullptr, 4096, 768, 1.0f, (b - 512) & 63, (b - 512) >> 6);
}

// output projection + residual
__global__ __launch_bounds__(256) void gemm_proj(const u16* __restrict__ woB, const u16* __restrict__ OtT,
                                                 void* __restrict__ Dv, const float* __restrict__ bo,
                                                 const float* __restrict__ res) {
  __shared__ u16 aT[3][128 * 64];
  __shared__ u16 bT[3][64 * 64];
  gemm_body<0, false, true>(&aT[0][0], &bT[0][0], woB, OtT, Dv, bo, res, 4096, 512, 1.0f,
                            blockIdx.x & 63, blockIdx.x >> 6);
}

// ---------------- flash attention, KV-split x2, register-resident P ----------
// Counted-vmcnt pipeline: K 3-buf (2-tile lookahead), V 2-buf (1-tile), one
// barrier per iter, never a full drain except last iter.
__global__ __launch_bounds__(256) void attn_kernel(const u16* __restrict__ QT,
                                                   const u16* __restrict__ KT,
                                                   const u16* __restrict__ V,
                                                   u16* __restrict__ Opart,
                                                   float* __restrict__ Mb,
                                                   float* __restrict__ Lb) {
  __shared__ u16 kbuf[3][64 * 64];
  __shared__ u16 vbuf[2][64 * 64];
  const int t = threadIdx.x;
  const int lane = t & 63, w = t >> 6;
  const int l15 = lane & 15, l4 = lane >> 4;
  // XCD swizzle: 128 consecutive work-ids (2 head-halves) per XCD
  int bid = blockIdx.z * 512 + blockIdx.y * 64 + blockIdx.x;
  bid = (bid & 7) * 128 + (bid >> 3);
  const int z = bid >> 9;
  const int h = (bid >> 6) & 7;
  const int q0 = (bid & 63) * 64;
  const int tile0 = z * 32;
  const int r_st = t >> 3, slot = t & 7;

  const int qrow = q0 + w * 16 + l15;
  bf16x8 qa0 = *reinterpret_cast<const bf16x8*>(QT + (size_t)qrow * 512 + h * 64 + l4 * 8);
  bf16x8 qa1 = *reinterpret_cast<const bf16x8*>(QT + (size_t)qrow * 512 + h * 64 + 32 + l4 * 8);

  f32x4 o_acc[4] = {};
  float m_run = -1e30f, l_run = 0.f;

  auto stageK = [&](int tile, int b) {
#pragma unroll
    for (int q = 0; q < 2; ++q) {
      int row = q * 32 + r_st;
      int so = (slot ^ (row & 7)) * 8;
      gload_lds16(KT + (size_t)(tile * 64 + row) * 512 + h * 64 + so,
                  (char*)kbuf[b] + q * 4096 + w * 1024);
    }
  };
  // V: chunk-permuted source (perm(s)=(s&1)*4+(s>>1)) composed with row-XOR so
  // the PV read slots become (l4+4kk)^rowsw — same low-conflict pattern as K.
  auto stageV = [&](int tile, int b) {
#pragma unroll
    for (int q = 0; q < 2; ++q) {
      int row = q * 32 + r_st;
      int so = ((((slot & 1) * 4 + (slot >> 1)) ^ (row & 7)) * 8);
      gload_lds16(V + (size_t)(h * 64 + row) * 4096 + tile * 64 + so,
                  (char*)vbuf[b] + q * 4096 + w * 1024);
    }
  };

  // prologue: K0, V0, K1 (order matters for vmcnt counts)
  stageK(tile0 + 0, 0);
  stageV(tile0 + 0, 0);
  stageK(tile0 + 1, 1);

  for (int kt = 0; kt < 32; ++kt) {
    const int kc = kt % 3, vc = kt & 1;
    // steady state outstanding (oldest first): V(kt)x2, K(kt+1)x2 -> wait 2
    if (kt < 31) asm volatile("s_waitcnt vmcnt(2)\n\ts_barrier" ::: "memory");
    else         asm volatile("s_waitcnt vmcnt(0)\n\ts_barrier" ::: "memory");
    if (kt + 1 < 32) stageV(tile0 + kt + 1, vc ^ 1);
    if (kt + 2 < 32) stageK(tile0 + kt + 2, (kt + 2) % 3);

    // swapped QK^T: s[n][r] = S[q=l15][ctx = n*16 + l4*4 + r]  (log2 units)
    f32x4 s[4];
#pragma unroll
    for (int n = 0; n < 4; ++n) {
      int row = n * 16 + l15;
      int sw = (row & 7) << 4;
      bf16x8 kb0 = *reinterpret_cast<const bf16x8*>((const char*)kbuf[kc] + row * 128 + ((l4 * 16) ^ sw));
      bf16x8 kb1 = *reinterpret_cast<const bf16x8*>((const char*)kbuf[kc] + row * 128 + ((l4 * 16 + 64) ^ sw));
      f32x4 z4 = {};
      z4 = __builtin_amdgcn_mfma_f32_16x16x32_bf16(kb0, qa0, z4, 0, 0, 0);
      z4 = __builtin_amdgcn_mfma_f32_16x16x32_bf16(kb1, qa1, z4, 0, 0, 0);
      s[n] = z4;
    }

    // in-lane row max, then 2 cross-lane steps over l4 via permlane (VALU, not DS)
    float a0 = fmaxf(fmaxf(s[0][0], s[0][1]), s[0][2]);
    float a1 = fmaxf(fmaxf(s[0][3], s[1][0]), s[1][1]);
    float a2 = fmaxf(fmaxf(s[1][2], s[1][3]), s[2][0]);
    float a3 = fmaxf(fmaxf(s[2][1], s[2][2]), s[2][3]);
    float a4 = fmaxf(fmaxf(s[3][0], s[3][1]), s[3][2]);
    float mx = fmaxf(fmaxf(fmaxf(a0, a1), fmaxf(a2, a3)), fmaxf(a4, s[3][3]));
    {
      float p1 = mx, p2 = mx;
      asm volatile("v_permlane16_swap_b32 %0, %1" : "+v"(p1), "+v"(p2));
      mx = fmaxf(mx, p1);
      float q1 = mx, q2 = mx;
      asm volatile("v_permlane32_swap_b32 %0, %1" : "+v"(q1), "+v"(q2));
      mx = fmaxf(mx, q1);
    }

    if (__any(mx > m_run + 11.5437f)) {  // defer-max (T13), 8 nats in log2
      float mn = fmaxf(m_run, mx);
      float al = exp2f(m_run - mn);
      m_run = mn;
      l_run *= al;
      float ar0 = __shfl(al, l4 * 4 + 0, 64);
      float ar1 = __shfl(al, l4 * 4 + 1, 64);
      float ar2 = __shfl(al, l4 * 4 + 2, 64);
      float ar3 = __shfl(al, l4 * 4 + 3, 64);
#pragma unroll
      for (int dt = 0; dt < 4; ++dt) {
        o_acc[dt][0] *= ar0; o_acc[dt][1] *= ar1;
        o_acc[dt][2] *= ar2; o_acc[dt][3] *= ar3;
      }
    }

    float ps0 = 0.f, ps1 = 0.f, ps2 = 0.f, ps3 = 0.f;
#pragma unroll
    for (int n = 0; n < 4; ++n) {
      float p0 = exp2f(s[n][0] - m_run);
      float p1 = exp2f(s[n][1] - m_run);
      float p2 = exp2f(s[n][2] - m_run);
      float p3 = exp2f(s[n][3] - m_run);
      s[n][0] = p0; s[n][1] = p1; s[n][2] = p2; s[n][3] = p3;
      ps0 += p0; ps1 += p1; ps2 += p2; ps3 += p3;
    }
    l_run += (ps0 + ps1) + (ps2 + ps3);

    // P -> bf16 A-fragments fully in registers: 8 cvt_pk + 4 permlane16_swap
    uint32_t u00 = cvtpk(s[0][0], s[0][1]), u01 = cvtpk(s[0][2], s[0][3]);
    uint32_t u10 = cvtpk(s[1][0], s[1][1]), u11 = cvtpk(s[1][2], s[1][3]);
    uint32_t u20 = cvtpk(s[2][0], s[2][1]), u21 = cvtpk(s[2][2], s[2][3]);
    uint32_t u30 = cvtpk(s[3][0], s[3][1]), u31 = cvtpk(s[3][2], s[3][3]);
    asm volatile("v_permlane16_swap_b32 %0, %1" : "+v"(u00), "+v"(u20));
    asm volatile("v_permlane16_swap_b32 %0, %1" : "+v"(u01), "+v"(u21));
    asm volatile("v_permlane16_swap_b32 %0, %1" : "+v"(u10), "+v"(u30));
    asm volatile("v_permlane16_swap_b32 %0, %1" : "+v"(u11), "+v"(u31));
    int4 pa0i = {(int)u00, (int)u01, (int)u20, (int)u21};
    int4 pa1i = {(int)u10, (int)u11, (int)u30, (int)u31};
    bf16x8 pa0 = __builtin_bit_cast(bf16x8, pa0i);
    bf16x8 pa1 = __builtin_bit_cast(bf16x8, pa1i);

    // O += P V   (V chunk-permuted: read slots l4 and l4+4, K-pattern banks)
#pragma unroll
    for (int dt = 0; dt < 4; ++dt) {
      int drow = dt * 16 + l15;
      int sw = (drow & 7) << 4;
      bf16x8 vb0 = *reinterpret_cast<const bf16x8*>((const char*)vbuf[vc] + drow * 128 + ((l4 * 16) ^ sw));
      o_acc[dt] = __builtin_amdgcn_mfma_f32_16x16x32_bf16(pa0, vb0, o_acc[dt], 0, 0, 0);
      bf16x8 vb1 = *reinterpret_cast<const bf16x8*>((const char*)vbuf[vc] + drow * 128 + ((l4 * 16 + 64) ^ sw));
      o_acc[dt] = __builtin_amdgcn_mfma_f32_16x16x32_bf16(pa1, vb1, o_acc[dt], 0, 0, 0);
    }
  }

  l_run += __shfl_xor(l_run, 16, 64);
  l_run += __shfl_xor(l_run, 32, 64);

#pragma unroll
  for (int r = 0; r < 4; ++r) {
    int orow = q0 + w * 16 + l4 * 4 + r;
#pragma unroll
    for (int dt = 0; dt < 4; ++dt)
      Opart[((size_t)z * 4096 + orow) * 512 + h * 64 + dt * 16 + l15] = f2bf(o_acc[dt][r]);
  }
  if (l4 == 0) {
    int q = q0 + w * 16 + l15;
    Mb[z * 32768 + h * 4096 + q] = m_run;
    Lb[z * 32768 + h * 4096 + q] = l_run;
  }
}

// ---------------- combine two KV-split partials ------------------------------
__global__ __launch_bounds__(256) void attn_combine(const u16* __restrict__ Opart,
                                                    const float* __restrict__ Mb,
                                                    const float* __restrict__ Lb,
                                                    u16* __restrict__ OtT) {
  int idx = blockIdx.x * 256 + threadIdx.x;
  int q = idx >> 7;
  int c = (idx & 127) * 4;
  int h = c >> 6;
  float m0 = Mb[h * 4096 + q], m1 = Mb[32768 + h * 4096 + q];
  float l0 = Lb[h * 4096 + q], l1 = Lb[32768 + h * 4096 + q];
  float M = fmaxf(m0, m1);
  float w0 = exp2f(m0 - M), w1 = exp2f(m1 - M);
  float inv = 1.f / (w0 * l0 + w1 * l1);
  w0 *= inv; w1 *= inv;
  uint2 a = *reinterpret_cast<const uint2*>(Opart + (size_t)q * 512 + c);
  uint2 b = *reinterpret_cast<const uint2*>(Opart + (size_t)4096 * 512 + (size_t)q * 512 + c);
  u16 o[4];
  o[0] = f2bf(bf2f((u16)(a.x & 0xFFFF)) * w0 + bf2f((u16)(b.x & 0xFFFF)) * w1);
  o[1] = f2bf(bf2f((u16)(a.x >> 16)) * w0 + bf2f((u16)(b.x >> 16)) * w1);
  o[2] = f2bf(bf2f((u16)(a.y & 0xFFFF)) * w0 + bf2f((u16)(b.y & 0xFFFF)) * w1);
  o[3] = f2bf(bf2f((u16)(a.y >> 16)) * w0 + bf2f((u16)(b.y >> 16)) * w1);
  *reinterpret_cast<uint2*>(OtT + (size_t)q * 512 + c) = *reinterpret_cast<const uint2*>(o);
}

// ---------------- host launch -------------------------------------------------
extern "C" void kernel_launch(void* const* d_in, const int* in_sizes, int n_in,
                              void* d_out, int out_size, void* d_ws, size_t ws_size,
                              hipStream_t stream) {
  const float* x    = (const float*)d_in[0];
  const float* ctx  = (const float*)d_in[1];
  const float* gn_w = (const float*)d_in[2];
  const float* gn_b = (const float*)d_in[3];
  const float* wq   = (const float*)d_in[4];
  const float* bq   = (const float*)d_in[5];
  const float* wk   = (const float*)d_in[6];
  const float* bk   = (const float*)d_in[7];
  const float* wv   = (const float*)d_in[8];
  const float* bv   = (const float*)d_in[9];
  const float* wo   = (const float*)d_in[10];
  const float* bo   = (const float*)d_in[11];

  char* ws = (char*)d_ws;
  float* gsum  = (float*)ws;                      // 32 f32
  float* gsum2 = gsum + 32;                       // 32 f32
  u16* wqB    = (u16*)(ws + 4096);
  u16* wkB    = wqB + 512 * 512;
  u16* wvB    = wkB + 512 * 768;
  u16* woB    = wvB + 512 * 768;
  u16* hT     = woB + 512 * 512;                  // [4096][512]
  u16* ctxT   = hT + 4096 * 512;                  // [4096][768]
  u16* QT     = ctxT + 4096 * 768;                // [4096][512]
  u16* KT     = QT + 4096 * 512;                  // [4096][512]
  u16* Vb     = KT + 4096 * 512;                  // [512][4096]
  u16* OtT    = Vb + (size_t)512 * 4096;          // [4096][512]
  float* Mb   = (float*)(OtT + (size_t)4096 * 512);  // [2][8][4096]
  float* Lb   = Mb + 65536;
  u16* Opart  = hT;  // overlays hT + first 4MB of ctxT (dead by attn time)

  (void)hipMemsetAsync(gsum, 0, 256, stream);
  gn_partial<<<256, 256, 0, stream>>>(x, gsum, gsum2);
  prep<<<2560, 256, 0, stream>>>(wq, wqB, wk, wkB, wv, wvB, wo, woB,
                                 x, hT, ctx, ctxT, gn_w, gn_b, gsum, gsum2);

  gemm_all<<<768, 256, 0, stream>>>(hT, ctxT, wqB, wkB, wvB, QT, KT, Vb, bq, bk, bv);

  attn_kernel<<<dim3(64, 8, 2), 256, 0, stream>>>(QT, KT, Vb, Opart, Mb, Lb);
  attn_combine<<<2048, 256, 0, stream>>>(Opart, Mb, Lb, OtT);

  gemm_proj<<<256, 256, 0, stream>>>(woB, OtT, (float*)d_out, bo, x);
}